// Round 5
// baseline (745.278 us; speedup 1.0000x reference)
//
#include <hip/hip_runtime.h>

// ---------------------------------------------------------------------------
// 4-layer GCN, restructured:
//   P(Y)_d = isd_d * (sum_{e:dst=d} Ys_src + Ys_d)  with Ys = isd*Y (pre-scaled)
//   gcn(Z,W,b) = P(Z@W) + b = P(Z)@W + b   (commute to aggregate in smaller dim)
// L1: Ys1 = isd*(X@W1); z1 = relu(P' + b1)            [agg on 128]
// L2: Ys2 = isd*(z1@W2); zs2 = isd*(P' + b2)          [agg on 64, post-scaled]
// L3: g2 = P(z2) from zs2 [agg on 64]; z3 = relu(g2@W3 + b3)
// L4: Ys4 = isd*(z3@W4); out = P' + b4 -> d_out       [agg on 128]
// ---------------------------------------------------------------------------

static __global__ void hist_kernel(const int* __restrict__ dst, int* __restrict__ counts, int E) {
  int i = blockIdx.x * blockDim.x + threadIdx.x;
  if (i < E) atomicAdd(&counts[dst[i]], 1);
}

static __global__ void isd_kernel(const int* __restrict__ counts, float* __restrict__ isd, int n) {
  int i = blockIdx.x * blockDim.x + threadIdx.x;
  if (i < n) isd[i] = rsqrtf((float)counts[i] + 1.0f);
}

// 3-pass exclusive scan
static __global__ void scan1_kernel(const int* __restrict__ counts, int* __restrict__ row_ptr,
                                    int* __restrict__ blksum, int n) {
  __shared__ int sh[256];
  int i = blockIdx.x * 256 + threadIdx.x;
  int v = (i < n) ? counts[i] : 0;
  sh[threadIdx.x] = v;
  __syncthreads();
  for (int off = 1; off < 256; off <<= 1) {
    int t = ((int)threadIdx.x >= off) ? sh[threadIdx.x - off] : 0;
    __syncthreads();
    sh[threadIdx.x] += t;
    __syncthreads();
  }
  if (i < n) row_ptr[i] = sh[threadIdx.x] - v;
  if (threadIdx.x == 255) blksum[blockIdx.x] = sh[255];
}

static __global__ void scan2_kernel(const int* __restrict__ blksum, int* __restrict__ blkoff,
                                    int* __restrict__ row_ptr, int nb, int n) {
  __shared__ int sh[1024];
  int v = ((int)threadIdx.x < nb) ? blksum[threadIdx.x] : 0;
  sh[threadIdx.x] = v;
  __syncthreads();
  for (int off = 1; off < 1024; off <<= 1) {
    int t = ((int)threadIdx.x >= off) ? sh[threadIdx.x - off] : 0;
    __syncthreads();
    sh[threadIdx.x] += t;
    __syncthreads();
  }
  if ((int)threadIdx.x < nb) blkoff[threadIdx.x] = sh[threadIdx.x] - v;
  if ((int)threadIdx.x == nb - 1) row_ptr[n] = sh[threadIdx.x];
}

static __global__ void scan3_kernel(int* __restrict__ row_ptr, const int* __restrict__ blkoff, int n) {
  int i = blockIdx.x * 256 + threadIdx.x;
  if (i < n) row_ptr[i] += blkoff[blockIdx.x];
}

static __global__ void fill_kernel(const int* __restrict__ src, const int* __restrict__ dst,
                                   const int* __restrict__ row_ptr, int* __restrict__ cursor,
                                   int* __restrict__ csr_src, int E) {
  int i = blockIdx.x * blockDim.x + threadIdx.x;
  if (i < E) {
    int d = dst[i];
    int p = row_ptr[d] + atomicAdd(&cursor[d], 1);
    csr_src[p] = src[i];
  }
}

// ---------------------------------------------------------------------------
// GEMM: H[n,NOUT] = epi(X[n,K] @ W[K,NOUT]). 64x64 tile, 256 thr, 4x4/thread.
// k-loop by 8 (NOT full unroll: r2 showed full unroll -> spill -> GB scratch).
// W chunk register-double-buffered: next chunk's global loads issue before the
// barrier; regs are private so the barrier doesn't drain vmcnt -> overlap.
// EPI 0: H = isd[row] * acc     EPI 1: H = relu(acc + bias[col])
// ---------------------------------------------------------------------------
template<int K, int NOUT, int EPI>
__device__ __forceinline__ void gemm_body(const float* __restrict__ X, const float* __restrict__ W,
                                          const float* __restrict__ aux, float* __restrict__ H, int n) {
  constexpr int BM = 64, BN = 64;
  __shared__ float xs[BM][K + 4];
  __shared__ float wsh[64][BN];
  const int tid = threadIdx.x;
  const int bm = blockIdx.x * BM;
  const int bc = blockIdx.y * BN;

  // W chunk0 -> regs (overlaps with xs staging)
  float4 wbuf[4];
#pragma unroll
  for (int j = 0; j < 4; ++j) {
    int v = tid + 256 * j;
    int r = v >> 4, c4 = v & 15;
    wbuf[j] = *(const float4*)&W[(size_t)r * NOUT + bc + c4 * 4];
  }

  // stage X panel (whole K) once
  for (int v = tid; v < BM * (K / 4); v += 256) {
    int r = v / (K / 4), c4 = v % (K / 4);
    int gr = bm + r;
    float4 val = make_float4(0.f, 0.f, 0.f, 0.f);
    if (gr < n) val = *(const float4*)&X[(size_t)gr * K + c4 * 4];
    *(float4*)&xs[r][c4 * 4] = val;
  }

  const int ty = tid >> 4, tx = tid & 15;
  const int r0 = ty * 4, c0 = tx * 4;
  float acc[4][4];
#pragma unroll
  for (int i = 0; i < 4; ++i)
#pragma unroll
    for (int j = 0; j < 4; ++j) acc[i][j] = 0.f;

#pragma unroll 1
  for (int kb = 0; kb < K; kb += 64) {
    __syncthreads();  // prev compute done reading wsh; xs writes done (1st iter)
#pragma unroll
    for (int j = 0; j < 4; ++j) {
      int v = tid + 256 * j;
      int r = v >> 4, c4 = v & 15;
      *(float4*)&wsh[r][c4 * 4] = wbuf[j];
    }
    if (kb + 64 < K) {  // prefetch next W chunk into regs (in flight across barrier)
#pragma unroll
      for (int j = 0; j < 4; ++j) {
        int v = tid + 256 * j;
        int r = v >> 4, c4 = v & 15;
        wbuf[j] = *(const float4*)&W[(size_t)(kb + 64 + r) * NOUT + bc + c4 * 4];
      }
    }
    __syncthreads();  // wsh ready
#pragma unroll 1
    for (int k = 0; k < 64; k += 8) {
      float4 w0 = *(const float4*)&wsh[k + 0][c0];
      float4 w1 = *(const float4*)&wsh[k + 1][c0];
      float4 w2 = *(const float4*)&wsh[k + 2][c0];
      float4 w3 = *(const float4*)&wsh[k + 3][c0];
      float4 w4 = *(const float4*)&wsh[k + 4][c0];
      float4 w5 = *(const float4*)&wsh[k + 5][c0];
      float4 w6 = *(const float4*)&wsh[k + 6][c0];
      float4 w7 = *(const float4*)&wsh[k + 7][c0];
#pragma unroll
      for (int i = 0; i < 4; ++i) {
        float4 a0 = *(const float4*)&xs[r0 + i][kb + k];
        float4 a1 = *(const float4*)&xs[r0 + i][kb + k + 4];
        acc[i][0] += a0.x * w0.x + a0.y * w1.x + a0.z * w2.x + a0.w * w3.x
                   + a1.x * w4.x + a1.y * w5.x + a1.z * w6.x + a1.w * w7.x;
        acc[i][1] += a0.x * w0.y + a0.y * w1.y + a0.z * w2.y + a0.w * w3.y
                   + a1.x * w4.y + a1.y * w5.y + a1.z * w6.y + a1.w * w7.y;
        acc[i][2] += a0.x * w0.z + a0.y * w1.z + a0.z * w2.z + a0.w * w3.z
                   + a1.x * w4.z + a1.y * w5.z + a1.z * w6.z + a1.w * w7.z;
        acc[i][3] += a0.x * w0.w + a0.y * w1.w + a0.z * w2.w + a0.w * w3.w
                   + a1.x * w4.w + a1.y * w5.w + a1.z * w6.w + a1.w * w7.w;
      }
    }
  }

  float4 bv = make_float4(0.f, 0.f, 0.f, 0.f);
  if (EPI == 1) bv = *(const float4*)&aux[bc + c0];
#pragma unroll
  for (int i = 0; i < 4; ++i) {
    int gr = bm + r0 + i;
    if (gr < n) {
      float4 o;
      if (EPI == 0) {
        float s = aux[gr];
        o = make_float4(acc[i][0] * s, acc[i][1] * s, acc[i][2] * s, acc[i][3] * s);
      } else {
        o = make_float4(fmaxf(acc[i][0] + bv.x, 0.f), fmaxf(acc[i][1] + bv.y, 0.f),
                        fmaxf(acc[i][2] + bv.z, 0.f), fmaxf(acc[i][3] + bv.w, 0.f));
      }
      *(float4*)&H[(size_t)gr * NOUT + bc + c0] = o;
    }
  }
}

#define DEF_GEMM(NAME, K, NOUT, EPI)                                                     \
  __global__ __launch_bounds__(256, 2) void NAME(const float* __restrict__ X,            \
                                                 const float* __restrict__ W,            \
                                                 const float* __restrict__ aux,          \
                                                 float* __restrict__ H, int n) {         \
    gemm_body<K, NOUT, EPI>(X, W, aux, H, n);                                            \
  }
DEF_GEMM(gemm1_k128_n128_scale, 128, 128, 0)
DEF_GEMM(gemm2_k128_n64_scale, 128, 64, 0)
DEF_GEMM(gemm3_k64_n128_biasrelu, 64, 128, 1)
DEF_GEMM(gemm4_k128_n128_scale, 128, 128, 0)

// ---------------------------------------------------------------------------
// Aggregation over pre-scaled rows hs: acc_d = sum hs[src] ; then
//   t = isd_d * (acc + hs_d); [+bias]; [relu]; [*isd_d]  -> out
// D=128: 1 node/wave (64 lanes x float2). D=64: 2 nodes/wave (32 lanes x float2).
// Indices software-pipelined: next 4 idx loads issue while current 4 rows fly.
// ---------------------------------------------------------------------------
template<int D, bool RELU, bool HASBIAS, bool POSTSCALE>
__device__ __forceinline__ void agg_body(const float* __restrict__ hs, const int* __restrict__ row_ptr,
                                         const int* __restrict__ csr_src, const float* __restrict__ isd,
                                         const float* __restrict__ bias, float* __restrict__ out, int n) {
  int gt = blockIdx.x * blockDim.x + threadIdx.x;
  int gw, l;
  if (D == 128) {
    gw = gt >> 6;
    l = threadIdx.x & 63;
  } else {  // two nodes per wave, 32 lanes each
    gw = (gt >> 6) * 2 + ((threadIdx.x >> 5) & 1);
    l = threadIdx.x & 31;
  }
  if (gw >= n) return;

  const float* base = hs + (size_t)gw * D + l * 2;
  // hoist self-row / isd / bias loads: independent, issue early
  float wd = isd[gw];
  float2 hv = *(const float2*)base;
  float2 bv = make_float2(0.f, 0.f);
  if (HASBIAS) bv = *(const float2*)(bias + l * 2);

  int beg = row_ptr[gw], end = row_ptr[gw + 1];
  float acc0 = 0.f, acc1 = 0.f;

  int e = beg;
  int s0 = 0, s1 = 0, s2 = 0, s3 = 0;
  if (e + 4 <= end) {
    s0 = csr_src[e + 0]; s1 = csr_src[e + 1];
    s2 = csr_src[e + 2]; s3 = csr_src[e + 3];
  }
  while (e + 4 <= end) {
    float2 v0 = *(const float2*)(hs + (size_t)s0 * D + l * 2);
    float2 v1 = *(const float2*)(hs + (size_t)s1 * D + l * 2);
    float2 v2 = *(const float2*)(hs + (size_t)s2 * D + l * 2);
    float2 v3 = *(const float2*)(hs + (size_t)s3 * D + l * 2);
    int en = e + 4;
    if (en + 4 <= end) {  // prefetch next 4 idx (independent of v*)
      s0 = csr_src[en + 0]; s1 = csr_src[en + 1];
      s2 = csr_src[en + 2]; s3 = csr_src[en + 3];
    }
    acc0 += (v0.x + v1.x) + (v2.x + v3.x);
    acc1 += (v0.y + v1.y) + (v2.y + v3.y);
    e = en;
  }
  for (; e < end; ++e) {
    int s = csr_src[e];
    float2 v = *(const float2*)(hs + (size_t)s * D + l * 2);
    acc0 += v.x;
    acc1 += v.y;
  }

  float o0 = wd * (acc0 + hv.x);
  float o1 = wd * (acc1 + hv.y);
  if (HASBIAS) { o0 += bv.x; o1 += bv.y; }
  if (RELU) { o0 = fmaxf(o0, 0.f); o1 = fmaxf(o1, 0.f); }
  if (POSTSCALE) { o0 *= wd; o1 *= wd; }
  *(float2*)(out + (size_t)gw * D + l * 2) = make_float2(o0, o1);
}

#define DEF_AGG(NAME, D, RELU, HASBIAS, POSTSCALE)                                         \
  __global__ void NAME(const float* __restrict__ hs, const int* __restrict__ row_ptr,      \
                       const int* __restrict__ csr_src, const float* __restrict__ isd,     \
                       const float* __restrict__ bias, float* __restrict__ out, int n) {   \
    agg_body<D, RELU, HASBIAS, POSTSCALE>(hs, row_ptr, csr_src, isd, bias, out, n);        \
  }
DEF_AGG(agg1_d128_biasrelu, 128, true, true, false)
DEF_AGG(agg2_d64_bias_postscale, 64, false, true, true)
DEF_AGG(agg3_d64_plain, 64, false, false, false)
DEF_AGG(agg4_d128_bias, 128, false, true, false)

static inline size_t align_up(size_t x, size_t a) { return (x + a - 1) & ~(a - 1); }

extern "C" void kernel_launch(void* const* d_in, const int* in_sizes, int n_in,
                              void* d_out, int out_size, void* d_ws, size_t ws_size,
                              hipStream_t stream) {
  const float* X  = (const float*)d_in[0];
  const float* W1 = (const float*)d_in[1];
  const float* b1 = (const float*)d_in[2];
  const float* W2 = (const float*)d_in[3];
  const float* b2 = (const float*)d_in[4];
  const float* W3 = (const float*)d_in[5];
  const float* b3 = (const float*)d_in[6];
  const float* W4 = (const float*)d_in[7];
  const float* b4 = (const float*)d_in[8];
  const int*   ei = (const int*)d_in[9];

  const int N = in_sizes[0] / 128;
  const int E = in_sizes[9] / 2;
  const int* src = ei;
  const int* dst = ei + E;
  float* OUT = (float*)d_out;

  char* ws = (char*)d_ws;
  size_t off = 0;
  auto alloc = [&](size_t bytes) { void* p = ws + off; off = align_up(off + bytes, 256); return p; };
  int*   counts  = (int*)alloc((size_t)N * 4);
  int*   cursor  = (int*)alloc((size_t)N * 4);
  int*   row_ptr = (int*)alloc(((size_t)N + 1) * 4);
  float* isd     = (float*)alloc((size_t)N * 4);
  int*   csr_src = (int*)alloc((size_t)E * 4);
  int*   blksum  = (int*)alloc(1024 * 4);
  int*   blkoff  = (int*)alloc(1024 * 4);
  float* A       = (float*)alloc((size_t)N * 128 * 4);
  float* A_lo = A;                   // N x 64 view
  float* A_hi = A + (size_t)N * 64;  // N x 64 view

  hipMemsetAsync(counts, 0, (size_t)N * 4, stream);
  hipMemsetAsync(cursor, 0, (size_t)N * 4, stream);

  int eb = (E + 255) / 256;
  int nb = (N + 255) / 256;  // 391 for N=100k, must be <= 1024 for scan2
  hist_kernel<<<eb, 256, 0, stream>>>(dst, counts, E);
  isd_kernel<<<nb, 256, 0, stream>>>(counts, isd, N);
  scan1_kernel<<<nb, 256, 0, stream>>>(counts, row_ptr, blksum, N);
  scan2_kernel<<<1, 1024, 0, stream>>>(blksum, blkoff, row_ptr, nb, N);
  scan3_kernel<<<nb, 256, 0, stream>>>(row_ptr, blkoff, N);
  fill_kernel<<<eb, 256, 0, stream>>>(src, dst, row_ptr, cursor, csr_src, E);

  const int gm = (N + 63) / 64;
  const int ab128 = (int)(((size_t)N * 64 + 255) / 256);
  const int ab64  = (int)(((size_t)N * 32 + 255) / 256);

  // L1: Ys1 = isd*(X@W1) -> A ; z1 = relu(P'+b1) -> OUT
  gemm1_k128_n128_scale<<<dim3(gm, 2), 256, 0, stream>>>(X, W1, isd, A, N);
  agg1_d128_biasrelu<<<ab128, 256, 0, stream>>>(A, row_ptr, csr_src, isd, b1, OUT, N);
  // L2: Ys2 = isd*(z1@W2) -> A_lo ; zs2 = isd*(P'+b2) -> A_hi
  gemm2_k128_n64_scale<<<dim3(gm, 1), 256, 0, stream>>>(OUT, W2, isd, A_lo, N);
  agg2_d64_bias_postscale<<<ab64, 256, 0, stream>>>(A_lo, row_ptr, csr_src, isd, b2, A_hi, N);
  // L3 (commuted): g2 = P(z2) from zs2 -> A_lo ; z3 = relu(g2@W3+b3) -> OUT
  agg3_d64_plain<<<ab64, 256, 0, stream>>>(A_hi, row_ptr, csr_src, isd, nullptr, A_lo, N);
  gemm3_k64_n128_biasrelu<<<dim3(gm, 2), 256, 0, stream>>>(A_lo, W3, b3, OUT, N);
  // L4: Ys4 = isd*(z3@W4) -> A ; out = P'+b4 -> OUT (final)
  gemm4_k128_n128_scale<<<dim3(gm, 2), 256, 0, stream>>>(OUT, W4, isd, A, N);
  agg4_d128_bias<<<ab128, 256, 0, stream>>>(A, row_ptr, csr_src, isd, b4, OUT, N);
}

// Round 6
// 616.528 us; speedup vs baseline: 1.2088x; 1.2088x over previous
//
#include <hip/hip_runtime.h>
#include <hip/hip_fp16.h>

// ---------------------------------------------------------------------------
// 4-layer GCN, restructured:
//   P(Y)_d = isd_d * (sum_{e:dst=d} Ys_src + Ys_d)  with Ys = isd*Y (pre-scaled)
//   gcn(Z,W,b) = P(Z@W) + b = P(Z)@W + b   (commute to aggregate in smaller dim)
// Gathered arrays (hs) are fp16 (halves the 8x-XCD-replicated L3 traffic);
// all accumulation fp32.
// L1: F=fp16(isd*(X@W1));  z1 = relu(P'+b1) -> OUT            [agg 128]
// L2: Fa=fp16(isd*(z1@W2)); Fb = fp16(isd*(P'+b2))            [agg 64]
// L3: g2 = P' from Fb -> A_lo (fp32); z3 = relu(g2@W3+b3) -> OUT
// L4: F=fp16(isd*(z3@W4));  out = P'+b4 -> d_out              [agg 128]
// ---------------------------------------------------------------------------

static __global__ void hist_kernel(const int* __restrict__ dst, int* __restrict__ counts, int E) {
  int i = blockIdx.x * blockDim.x + threadIdx.x;
  if (i < E) atomicAdd(&counts[dst[i]], 1);
}

static __global__ void isd_kernel(const int* __restrict__ counts, float* __restrict__ isd, int n) {
  int i = blockIdx.x * blockDim.x + threadIdx.x;
  if (i < n) isd[i] = rsqrtf((float)counts[i] + 1.0f);
}

// 3-pass exclusive scan
static __global__ void scan1_kernel(const int* __restrict__ counts, int* __restrict__ row_ptr,
                                    int* __restrict__ blksum, int n) {
  __shared__ int sh[256];
  int i = blockIdx.x * 256 + threadIdx.x;
  int v = (i < n) ? counts[i] : 0;
  sh[threadIdx.x] = v;
  __syncthreads();
  for (int off = 1; off < 256; off <<= 1) {
    int t = ((int)threadIdx.x >= off) ? sh[threadIdx.x - off] : 0;
    __syncthreads();
    sh[threadIdx.x] += t;
    __syncthreads();
  }
  if (i < n) row_ptr[i] = sh[threadIdx.x] - v;
  if (threadIdx.x == 255) blksum[blockIdx.x] = sh[255];
}

static __global__ void scan2_kernel(const int* __restrict__ blksum, int* __restrict__ blkoff,
                                    int* __restrict__ row_ptr, int nb, int n) {
  __shared__ int sh[1024];
  int v = ((int)threadIdx.x < nb) ? blksum[threadIdx.x] : 0;
  sh[threadIdx.x] = v;
  __syncthreads();
  for (int off = 1; off < 1024; off <<= 1) {
    int t = ((int)threadIdx.x >= off) ? sh[threadIdx.x - off] : 0;
    __syncthreads();
    sh[threadIdx.x] += t;
    __syncthreads();
  }
  if ((int)threadIdx.x < nb) blkoff[threadIdx.x] = sh[threadIdx.x] - v;
  if ((int)threadIdx.x == nb - 1) row_ptr[n] = sh[threadIdx.x];
}

static __global__ void scan3_kernel(int* __restrict__ row_ptr, const int* __restrict__ blkoff, int n) {
  int i = blockIdx.x * 256 + threadIdx.x;
  if (i < n) row_ptr[i] += blkoff[blockIdx.x];
}

static __global__ void fill_kernel(const int* __restrict__ src, const int* __restrict__ dst,
                                   const int* __restrict__ row_ptr, int* __restrict__ cursor,
                                   int* __restrict__ csr_src, int E) {
  int i = blockIdx.x * blockDim.x + threadIdx.x;
  if (i < E) {
    int d = dst[i];
    int p = row_ptr[d] + atomicAdd(&cursor[d], 1);
    csr_src[p] = src[i];
  }
}

// ---------------------------------------------------------------------------
// GEMM: H[n,NOUT] = epi(X[n,K] @ W[K,NOUT]). 64x64 tile, 256 thr, 4x4/thread.
// Per-64-col chunk staging of BOTH X and W (LDS 33.8KB -> 4 blocks/CU, was 2),
// both register-prefetched. Rolled k4 (full unroll -> spill, r2; k8 neutral, r5).
// EPI 0: fp16 out, H = fp16(isd[row] * acc)   EPI 1: fp32 out, relu(acc+bias)
// ---------------------------------------------------------------------------
template<int K, int NOUT, int EPI>
__device__ __forceinline__ void gemm_body(const float* __restrict__ X, const float* __restrict__ W,
                                          const float* __restrict__ aux, void* __restrict__ Hout, int n) {
  constexpr int BM = 64, BN = 64;
  __shared__ float xs[BM][64 + 4];
  __shared__ float wsh[64][BN];
  const int tid = threadIdx.x;
  const int bm = blockIdx.x * BM;
  const int bc = blockIdx.y * BN;

  const int sr = tid >> 4;          // staging row 0..15 step -> +16 per j
  const int sc4 = tid & 15;         // staging col/4

  // chunk0 -> regs
  float4 wbuf[4], xbuf[4];
#pragma unroll
  for (int j = 0; j < 4; ++j) {
    int r = sr + 16 * j;
    wbuf[j] = *(const float4*)&W[(size_t)r * NOUT + bc + sc4 * 4];
    int gr = bm + r;
    xbuf[j] = make_float4(0.f, 0.f, 0.f, 0.f);
    if (gr < n) xbuf[j] = *(const float4*)&X[(size_t)gr * K + sc4 * 4];
  }

  const int ty = tid >> 4, tx = tid & 15;
  const int r0 = ty * 4, c0 = tx * 4;
  float acc[4][4];
#pragma unroll
  for (int i = 0; i < 4; ++i)
#pragma unroll
    for (int j = 0; j < 4; ++j) acc[i][j] = 0.f;

#pragma unroll 1
  for (int kb = 0; kb < K; kb += 64) {
    __syncthreads();  // previous chunk consumed
#pragma unroll
    for (int j = 0; j < 4; ++j) {
      int r = sr + 16 * j;
      *(float4*)&wsh[r][sc4 * 4] = wbuf[j];
      *(float4*)&xs[r][sc4 * 4] = xbuf[j];
    }
    if (kb + 64 < K) {  // prefetch next chunk into regs (flies across barrier)
#pragma unroll
      for (int j = 0; j < 4; ++j) {
        int r = sr + 16 * j;
        wbuf[j] = *(const float4*)&W[(size_t)(kb + 64 + r) * NOUT + bc + sc4 * 4];
        int gr = bm + r;
        xbuf[j] = make_float4(0.f, 0.f, 0.f, 0.f);
        if (gr < n) xbuf[j] = *(const float4*)&X[(size_t)gr * K + kb + 64 + sc4 * 4];
      }
    }
    __syncthreads();  // LDS ready
#pragma unroll 1
    for (int k = 0; k < 64; k += 4) {
      float4 w0 = *(const float4*)&wsh[k + 0][c0];
      float4 w1 = *(const float4*)&wsh[k + 1][c0];
      float4 w2 = *(const float4*)&wsh[k + 2][c0];
      float4 w3 = *(const float4*)&wsh[k + 3][c0];
#pragma unroll
      for (int i = 0; i < 4; ++i) {
        float4 av = *(const float4*)&xs[r0 + i][k];
        acc[i][0] += av.x * w0.x + av.y * w1.x + av.z * w2.x + av.w * w3.x;
        acc[i][1] += av.x * w0.y + av.y * w1.y + av.z * w2.y + av.w * w3.y;
        acc[i][2] += av.x * w0.z + av.y * w1.z + av.z * w2.z + av.w * w3.z;
        acc[i][3] += av.x * w0.w + av.y * w1.w + av.z * w2.w + av.w * w3.w;
      }
    }
  }

  float4 bv = make_float4(0.f, 0.f, 0.f, 0.f);
  if (EPI == 1) bv = *(const float4*)&aux[bc + c0];
#pragma unroll
  for (int i = 0; i < 4; ++i) {
    int gr = bm + r0 + i;
    if (gr < n) {
      if (EPI == 0) {
        float s = aux[gr];
        __half2 p0 = __floats2half2_rn(acc[i][0] * s, acc[i][1] * s);
        __half2 p1 = __floats2half2_rn(acc[i][2] * s, acc[i][3] * s);
        __half* Hh = (__half*)Hout;
        *(__half2*)&Hh[(size_t)gr * NOUT + bc + c0]     = p0;
        *(__half2*)&Hh[(size_t)gr * NOUT + bc + c0 + 2] = p1;
      } else {
        float4 o = make_float4(fmaxf(acc[i][0] + bv.x, 0.f), fmaxf(acc[i][1] + bv.y, 0.f),
                               fmaxf(acc[i][2] + bv.z, 0.f), fmaxf(acc[i][3] + bv.w, 0.f));
        float* Hf = (float*)Hout;
        *(float4*)&Hf[(size_t)gr * NOUT + bc + c0] = o;
      }
    }
  }
}

#define DEF_GEMM(NAME, K, NOUT, EPI)                                                     \
  __global__ __launch_bounds__(256, 2) void NAME(const float* __restrict__ X,            \
                                                 const float* __restrict__ W,            \
                                                 const float* __restrict__ aux,          \
                                                 void* __restrict__ H, int n) {          \
    gemm_body<K, NOUT, EPI>(X, W, aux, H, n);                                            \
  }
DEF_GEMM(gemm1_k128_n128_scaleh, 128, 128, 0)
DEF_GEMM(gemm2_k128_n64_scaleh, 128, 64, 0)
DEF_GEMM(gemm3_k64_n128_biasrelu, 64, 128, 1)
DEF_GEMM(gemm4_k128_n128_scaleh, 128, 128, 0)

// ---------------------------------------------------------------------------
// Aggregation over fp16 pre-scaled rows hs: acc_d = sum hs[src] (fp32 acc);
//   t = isd_d*(acc + hs_d); [+bias]; [relu]; [*isd_d] -> out (fp32 or fp16)
// D=128: 1 node/wave (64 lanes x half2). D=64: 2 nodes/wave (32 lanes x half2).
// 4-edge unroll + idx pipeline for MLP.
// ---------------------------------------------------------------------------
template<int D, bool RELU, bool HASBIAS, bool POSTSCALE, bool OUTHALF>
__device__ __forceinline__ void agg_body(const __half* __restrict__ hs, const int* __restrict__ row_ptr,
                                         const int* __restrict__ csr_src, const float* __restrict__ isd,
                                         const float* __restrict__ bias, void* __restrict__ out, int n) {
  int gt = blockIdx.x * blockDim.x + threadIdx.x;
  int gw, l;
  if (D == 128) {
    gw = gt >> 6;
    l = threadIdx.x & 63;
  } else {  // two nodes per wave, 32 lanes each
    gw = (gt >> 6) * 2 + ((threadIdx.x >> 5) & 1);
    l = threadIdx.x & 31;
  }
  if (gw >= n) return;

  // hoisted independent loads
  float wd = isd[gw];
  float2 hv = __half22float2(*(const __half2*)(hs + (size_t)gw * D + l * 2));
  float2 bv = make_float2(0.f, 0.f);
  if (HASBIAS) bv = *(const float2*)(bias + l * 2);

  int beg = row_ptr[gw], end = row_ptr[gw + 1];
  float acc0 = 0.f, acc1 = 0.f;

  int e = beg;
  int s0 = 0, s1 = 0, s2 = 0, s3 = 0;
  if (e + 4 <= end) {
    s0 = csr_src[e + 0]; s1 = csr_src[e + 1];
    s2 = csr_src[e + 2]; s3 = csr_src[e + 3];
  }
  while (e + 4 <= end) {
    float2 v0 = __half22float2(*(const __half2*)(hs + (size_t)s0 * D + l * 2));
    float2 v1 = __half22float2(*(const __half2*)(hs + (size_t)s1 * D + l * 2));
    float2 v2 = __half22float2(*(const __half2*)(hs + (size_t)s2 * D + l * 2));
    float2 v3 = __half22float2(*(const __half2*)(hs + (size_t)s3 * D + l * 2));
    int en = e + 4;
    if (en + 4 <= end) {
      s0 = csr_src[en + 0]; s1 = csr_src[en + 1];
      s2 = csr_src[en + 2]; s3 = csr_src[en + 3];
    }
    acc0 += (v0.x + v1.x) + (v2.x + v3.x);
    acc1 += (v0.y + v1.y) + (v2.y + v3.y);
    e = en;
  }
  for (; e < end; ++e) {
    int s = csr_src[e];
    float2 v = __half22float2(*(const __half2*)(hs + (size_t)s * D + l * 2));
    acc0 += v.x;
    acc1 += v.y;
  }

  float o0 = wd * (acc0 + hv.x);
  float o1 = wd * (acc1 + hv.y);
  if (HASBIAS) { o0 += bv.x; o1 += bv.y; }
  if (RELU) { o0 = fmaxf(o0, 0.f); o1 = fmaxf(o1, 0.f); }
  if (POSTSCALE) { o0 *= wd; o1 *= wd; }
  if (OUTHALF) {
    *(__half2*)((__half*)out + (size_t)gw * D + l * 2) = __floats2half2_rn(o0, o1);
  } else {
    *(float2*)((float*)out + (size_t)gw * D + l * 2) = make_float2(o0, o1);
  }
}

#define DEF_AGG(NAME, D, RELU, HASBIAS, POSTSCALE, OUTHALF)                                \
  __global__ void NAME(const __half* __restrict__ hs, const int* __restrict__ row_ptr,     \
                       const int* __restrict__ csr_src, const float* __restrict__ isd,     \
                       const float* __restrict__ bias, void* __restrict__ out, int n) {    \
    agg_body<D, RELU, HASBIAS, POSTSCALE, OUTHALF>(hs, row_ptr, csr_src, isd, bias, out, n); \
  }
DEF_AGG(agg1_d128_biasrelu_f32, 128, true, true, false, false)
DEF_AGG(agg2_d64_bias_ps_f16, 64, false, true, true, true)
DEF_AGG(agg3_d64_plain_f32, 64, false, false, false, false)
DEF_AGG(agg4_d128_bias_f32, 128, false, true, false, false)

static inline size_t align_up(size_t x, size_t a) { return (x + a - 1) & ~(a - 1); }

extern "C" void kernel_launch(void* const* d_in, const int* in_sizes, int n_in,
                              void* d_out, int out_size, void* d_ws, size_t ws_size,
                              hipStream_t stream) {
  const float* X  = (const float*)d_in[0];
  const float* W1 = (const float*)d_in[1];
  const float* b1 = (const float*)d_in[2];
  const float* W2 = (const float*)d_in[3];
  const float* b2 = (const float*)d_in[4];
  const float* W3 = (const float*)d_in[5];
  const float* b3 = (const float*)d_in[6];
  const float* W4 = (const float*)d_in[7];
  const float* b4 = (const float*)d_in[8];
  const int*   ei = (const int*)d_in[9];

  const int N = in_sizes[0] / 128;
  const int E = in_sizes[9] / 2;
  const int* src = ei;
  const int* dst = ei + E;
  float* OUT = (float*)d_out;

  char* ws = (char*)d_ws;
  size_t off = 0;
  auto alloc = [&](size_t bytes) { void* p = ws + off; off = align_up(off + bytes, 256); return p; };
  int*    counts  = (int*)alloc((size_t)N * 4);
  int*    cursor  = (int*)alloc((size_t)N * 4);
  int*    row_ptr = (int*)alloc(((size_t)N + 1) * 4);
  float*  isd     = (float*)alloc((size_t)N * 4);
  int*    csr_src = (int*)alloc((size_t)E * 4);
  int*    blksum  = (int*)alloc(1024 * 4);
  int*    blkoff  = (int*)alloc(1024 * 4);
  __half* F       = (__half*)alloc((size_t)N * 128 * 2);  // fp16 gather buffer
  float*  G       = (float*)alloc((size_t)N * 64 * 4);    // fp32 g2
  __half* Fa = F;                    // N x 64 fp16 view
  __half* Fb = F + (size_t)N * 64;   // N x 64 fp16 view

  hipMemsetAsync(counts, 0, (size_t)N * 4, stream);
  hipMemsetAsync(cursor, 0, (size_t)N * 4, stream);

  int eb = (E + 255) / 256;
  int nb = (N + 255) / 256;  // 391 for N=100k, must be <= 1024 for scan2
  hist_kernel<<<eb, 256, 0, stream>>>(dst, counts, E);
  isd_kernel<<<nb, 256, 0, stream>>>(counts, isd, N);
  scan1_kernel<<<nb, 256, 0, stream>>>(counts, row_ptr, blksum, N);
  scan2_kernel<<<1, 1024, 0, stream>>>(blksum, blkoff, row_ptr, nb, N);
  scan3_kernel<<<nb, 256, 0, stream>>>(row_ptr, blkoff, N);
  fill_kernel<<<eb, 256, 0, stream>>>(src, dst, row_ptr, cursor, csr_src, E);

  const int gm = (N + 63) / 64;
  const int ab128 = (int)(((size_t)N * 64 + 255) / 256);
  const int ab64  = (int)(((size_t)N * 32 + 255) / 256);

  // L1: F = fp16(isd*(X@W1)) ; z1 = relu(P'+b1) -> OUT
  gemm1_k128_n128_scaleh<<<dim3(gm, 2), 256, 0, stream>>>(X, W1, isd, F, N);
  agg1_d128_biasrelu_f32<<<ab128, 256, 0, stream>>>(F, row_ptr, csr_src, isd, b1, OUT, N);
  // L2: Fa = fp16(isd*(z1@W2)) ; Fb = fp16(isd*(P'+b2))
  gemm2_k128_n64_scaleh<<<dim3(gm, 1), 256, 0, stream>>>(OUT, W2, isd, Fa, N);
  agg2_d64_bias_ps_f16<<<ab64, 256, 0, stream>>>(Fa, row_ptr, csr_src, isd, b2, Fb, N);
  // L3 (commuted): G = P(z2) from Fb ; z3 = relu(G@W3+b3) -> OUT
  agg3_d64_plain_f32<<<ab64, 256, 0, stream>>>(Fb, row_ptr, csr_src, isd, nullptr, G, N);
  gemm3_k64_n128_biasrelu<<<dim3(gm, 2), 256, 0, stream>>>(G, W3, b3, OUT, N);
  // L4: F = fp16(isd*(z3@W4)) ; out = P'+b4 -> OUT (final)
  gemm4_k128_n128_scaleh<<<dim3(gm, 2), 256, 0, stream>>>(OUT, W4, isd, F, N);
  agg4_d128_bias_f32<<<ab128, 256, 0, stream>>>(F, row_ptr, csr_src, isd, b4, OUT, N);
}

// Round 7
// 463.544 us; speedup vs baseline: 1.6078x; 1.3300x over previous
//
#include <hip/hip_runtime.h>
#include <hip/hip_fp16.h>

typedef _Float16 f16x8 __attribute__((ext_vector_type(8)));
typedef float f32x4 __attribute__((ext_vector_type(4)));

// ---------------------------------------------------------------------------
// 4-layer GCN, all intermediates fp16 (fp32 accumulate everywhere):
//   P(Y)_d = isd_d * (sum_{e:dst=d} Ys_src + Ys_d)  with Ys = isd*Y (pre-scaled)
// L1: B1=f16(isd*(X@W1));  B2=z1=f16(relu(P'+b1))       [agg 128]
// L2: Fa=f16(isd*(z1@W2)); Fb=f16(isd*(P'+b2))          [agg 64]
// L3: G=f16(P' from Fb);   B2=z3=f16(relu(G@W3+b3))     [agg 64]
// L4: B1=f16(isd*(z3@W4)); out=P'+b4 -> d_out (fp32)    [agg 128]
// GEMMs: MFMA 16x16x32 f16 (fp32 GEMM was LDS-throughput-bound at ~19% VALU).
// ---------------------------------------------------------------------------

static __global__ void hist_kernel(const int* __restrict__ dst, int* __restrict__ counts, int E) {
  int i = blockIdx.x * blockDim.x + threadIdx.x;
  if (i < E) atomicAdd(&counts[dst[i]], 1);
}

static __global__ void isd_kernel(const int* __restrict__ counts, float* __restrict__ isd, int n) {
  int i = blockIdx.x * blockDim.x + threadIdx.x;
  if (i < n) isd[i] = rsqrtf((float)counts[i] + 1.0f);
}

// 3-pass exclusive scan
static __global__ void scan1_kernel(const int* __restrict__ counts, int* __restrict__ row_ptr,
                                    int* __restrict__ blksum, int n) {
  __shared__ int sh[256];
  int i = blockIdx.x * 256 + threadIdx.x;
  int v = (i < n) ? counts[i] : 0;
  sh[threadIdx.x] = v;
  __syncthreads();
  for (int off = 1; off < 256; off <<= 1) {
    int t = ((int)threadIdx.x >= off) ? sh[threadIdx.x - off] : 0;
    __syncthreads();
    sh[threadIdx.x] += t;
    __syncthreads();
  }
  if (i < n) row_ptr[i] = sh[threadIdx.x] - v;
  if (threadIdx.x == 255) blksum[blockIdx.x] = sh[255];
}

static __global__ void scan2_kernel(const int* __restrict__ blksum, int* __restrict__ blkoff,
                                    int* __restrict__ row_ptr, int nb, int n) {
  __shared__ int sh[1024];
  int v = ((int)threadIdx.x < nb) ? blksum[threadIdx.x] : 0;
  sh[threadIdx.x] = v;
  __syncthreads();
  for (int off = 1; off < 1024; off <<= 1) {
    int t = ((int)threadIdx.x >= off) ? sh[threadIdx.x - off] : 0;
    __syncthreads();
    sh[threadIdx.x] += t;
    __syncthreads();
  }
  if ((int)threadIdx.x < nb) blkoff[threadIdx.x] = sh[threadIdx.x] - v;
  if ((int)threadIdx.x == nb - 1) row_ptr[n] = sh[threadIdx.x];
}

static __global__ void scan3_kernel(int* __restrict__ row_ptr, const int* __restrict__ blkoff, int n) {
  int i = blockIdx.x * 256 + threadIdx.x;
  if (i < n) row_ptr[i] += blkoff[blockIdx.x];
}

// fill via atomicSub on counts (counts is dead after isd+scan; saves cursor+memset)
static __global__ void fill_kernel(const int* __restrict__ src, const int* __restrict__ dst,
                                   const int* __restrict__ row_ptr, int* __restrict__ counts,
                                   int* __restrict__ csr_src, int E) {
  int i = blockIdx.x * blockDim.x + threadIdx.x;
  if (i < E) {
    int d = dst[i];
    int k = atomicSub(&counts[d], 1);  // k = remaining count, 1..deg
    csr_src[row_ptr[d] + k - 1] = src[i];
  }
}

// ---------------------------------------------------------------------------
// MFMA GEMM: H[n,NOUT](f16) = epi(X[n,K] @ W[K,NOUT]) ; fp32 accumulate.
// 64x64 tile, 256 thr = 4 waves, each wave a 32x32 quadrant (2x2 MFMA frags).
// A staged row-major f16 (converted if AHALF=0); W staged transposed f16
// bh[col][k] so B-fragments are contiguous b128 reads.
// Fragment maps (m89-verified D; standard A/B):
//   A[lane&15][ (lane>>4)*8 + j ], B[(lane>>4)*8 + j][lane&15],
//   D: row=(lane>>4)*4+reg, col=lane&15.
// EPI 0: H = f16(isd[row]*acc)    EPI 1: H = f16(relu(acc + bias[col]))
// ---------------------------------------------------------------------------
template<int K, int NOUT, bool AHALF, int EPI>
__device__ __forceinline__ void gemm_mfma_body(const void* __restrict__ Xin,
                                               const float* __restrict__ W,
                                               const float* __restrict__ aux,
                                               __half* __restrict__ H, int n) {
  __shared__ _Float16 ah[64][K + 8];
  __shared__ _Float16 bh[64][K + 8];
  const int tid = threadIdx.x;
  const int bm = blockIdx.x * 64;
  const int bc = blockIdx.y * 64;

  // ---- stage A (64 x K) ----
  if (AHALF) {
    const __half* Xh = (const __half*)Xin;
    for (int i = tid; i < 64 * (K / 8); i += 256) {
      int r = i / (K / 8), c8 = i % (K / 8);
      int gr = bm + r;
      f16x8 v = {};
      if (gr < n) v = *(const f16x8*)&Xh[(size_t)gr * K + c8 * 8];
      *(f16x8*)&ah[r][c8 * 8] = v;
    }
  } else {
    const float* Xf = (const float*)Xin;
    for (int i = tid; i < 64 * (K / 8); i += 256) {
      int r = i / (K / 8), c8 = i % (K / 8);
      int gr = bm + r;
      f16x8 v = {};
      if (gr < n) {
        float4 a = *(const float4*)&Xf[(size_t)gr * K + c8 * 8];
        float4 b = *(const float4*)&Xf[(size_t)gr * K + c8 * 8 + 4];
        v[0] = (_Float16)a.x; v[1] = (_Float16)a.y; v[2] = (_Float16)a.z; v[3] = (_Float16)a.w;
        v[4] = (_Float16)b.x; v[5] = (_Float16)b.y; v[6] = (_Float16)b.z; v[7] = (_Float16)b.w;
      }
      *(f16x8*)&ah[r][c8 * 8] = v;
    }
  }
  // ---- stage B transposed: bh[col][k] = W[k][bc+col] ----
  {
    const int nn = tid & 63;
    const int kq = tid >> 6;   // 0..3
    constexpr int KT = K / 4;  // k's per thread
#pragma unroll
    for (int k8 = 0; k8 < KT; k8 += 8) {
      int k0 = kq * KT + k8;
      f16x8 v;
#pragma unroll
      for (int j = 0; j < 8; ++j)
        v[j] = (_Float16)W[(size_t)(k0 + j) * NOUT + bc + nn];  // lanes: consecutive cols -> coalesced
      *(f16x8*)&bh[nn][k0] = v;
    }
  }
  __syncthreads();

  const int lane = tid & 63;
  const int wid = tid >> 6;
  const int wm = (wid >> 1) * 32;
  const int wn = (wid & 1) * 32;
  const int lr = lane & 15;
  const int lk = (lane >> 4) * 8;

  f32x4 acc[2][2] = {};
#pragma unroll
  for (int ks = 0; ks < K; ks += 32) {
    f16x8 a0 = *(const f16x8*)&ah[wm + lr][ks + lk];
    f16x8 a1 = *(const f16x8*)&ah[wm + 16 + lr][ks + lk];
    f16x8 b0 = *(const f16x8*)&bh[wn + lr][ks + lk];
    f16x8 b1 = *(const f16x8*)&bh[wn + 16 + lr][ks + lk];
    acc[0][0] = __builtin_amdgcn_mfma_f32_16x16x32_f16(a0, b0, acc[0][0], 0, 0, 0);
    acc[0][1] = __builtin_amdgcn_mfma_f32_16x16x32_f16(a0, b1, acc[0][1], 0, 0, 0);
    acc[1][0] = __builtin_amdgcn_mfma_f32_16x16x32_f16(a1, b0, acc[1][0], 0, 0, 0);
    acc[1][1] = __builtin_amdgcn_mfma_f32_16x16x32_f16(a1, b1, acc[1][1], 0, 0, 0);
  }

  // ---- epilogue ----
  float bcol0 = 0.f, bcol1 = 0.f;
  if (EPI == 1) {
    bcol0 = aux[bc + wn + lr];
    bcol1 = aux[bc + wn + 16 + lr];
  }
  const int rgrp = (lane >> 4) * 4;
#pragma unroll
  for (int tm = 0; tm < 2; ++tm) {
    int rb = bm + wm + tm * 16 + rgrp;
#pragma unroll
    for (int r = 0; r < 4; ++r) {
      int row = rb + r;
      if (row >= n) continue;
      float s = (EPI == 0) ? aux[row] : 0.f;
#pragma unroll
      for (int tn = 0; tn < 2; ++tn) {
        int col = bc + wn + tn * 16 + lr;
        float v = acc[tm][tn][r];
        if (EPI == 0) v *= s;
        else v = fmaxf(v + (tn ? bcol1 : bcol0), 0.f);
        H[(size_t)row * NOUT + col] = __float2half(v);
      }
    }
  }
}

#define DEF_GEMM(NAME, K, NOUT, AHALF, EPI)                                              \
  __global__ __launch_bounds__(256, 2) void NAME(const void* __restrict__ X,             \
                                                 const float* __restrict__ W,            \
                                                 const float* __restrict__ aux,          \
                                                 __half* __restrict__ H, int n) {        \
    gemm_mfma_body<K, NOUT, AHALF, EPI>(X, W, aux, H, n);                                \
  }
DEF_GEMM(gemm1_mfma_k128_n128, 128, 128, false, 0)
DEF_GEMM(gemm2_mfma_k128_n64, 128, 64, true, 0)
DEF_GEMM(gemm3_mfma_k64_n128, 64, 128, true, 1)
DEF_GEMM(gemm4_mfma_k128_n128, 128, 128, true, 0)

// ---------------------------------------------------------------------------
// Aggregation over fp16 pre-scaled rows hs: acc_d = sum hs[src] (fp32 acc);
//   t = isd_d*(acc + hs_d); [+bias]; [relu]; [*isd_d] -> out (fp32 or fp16)
// D=128: 1 node/wave (64 lanes x half2). D=64: 2 nodes/wave (32 lanes x half2).
// ---------------------------------------------------------------------------
template<int D, bool RELU, bool HASBIAS, bool POSTSCALE, bool OUTHALF>
__device__ __forceinline__ void agg_body(const __half* __restrict__ hs, const int* __restrict__ row_ptr,
                                         const int* __restrict__ csr_src, const float* __restrict__ isd,
                                         const float* __restrict__ bias, void* __restrict__ out, int n) {
  int gt = blockIdx.x * blockDim.x + threadIdx.x;
  int gw, l;
  if (D == 128) {
    gw = gt >> 6;
    l = threadIdx.x & 63;
  } else {
    gw = (gt >> 6) * 2 + ((threadIdx.x >> 5) & 1);
    l = threadIdx.x & 31;
  }
  if (gw >= n) return;

  float wd = isd[gw];
  float2 hv = __half22float2(*(const __half2*)(hs + (size_t)gw * D + l * 2));
  float2 bv = make_float2(0.f, 0.f);
  if (HASBIAS) bv = *(const float2*)(bias + l * 2);

  int beg = row_ptr[gw], end = row_ptr[gw + 1];
  float acc0 = 0.f, acc1 = 0.f;

  int e = beg;
  int s0 = 0, s1 = 0, s2 = 0, s3 = 0;
  if (e + 4 <= end) {
    s0 = csr_src[e + 0]; s1 = csr_src[e + 1];
    s2 = csr_src[e + 2]; s3 = csr_src[e + 3];
  }
  while (e + 4 <= end) {
    float2 v0 = __half22float2(*(const __half2*)(hs + (size_t)s0 * D + l * 2));
    float2 v1 = __half22float2(*(const __half2*)(hs + (size_t)s1 * D + l * 2));
    float2 v2 = __half22float2(*(const __half2*)(hs + (size_t)s2 * D + l * 2));
    float2 v3 = __half22float2(*(const __half2*)(hs + (size_t)s3 * D + l * 2));
    int en = e + 4;
    if (en + 4 <= end) {
      s0 = csr_src[en + 0]; s1 = csr_src[en + 1];
      s2 = csr_src[en + 2]; s3 = csr_src[en + 3];
    }
    acc0 += (v0.x + v1.x) + (v2.x + v3.x);
    acc1 += (v0.y + v1.y) + (v2.y + v3.y);
    e = en;
  }
  for (; e < end; ++e) {
    int s = csr_src[e];
    float2 v = __half22float2(*(const __half2*)(hs + (size_t)s * D + l * 2));
    acc0 += v.x;
    acc1 += v.y;
  }

  float o0 = wd * (acc0 + hv.x);
  float o1 = wd * (acc1 + hv.y);
  if (HASBIAS) { o0 += bv.x; o1 += bv.y; }
  if (RELU) { o0 = fmaxf(o0, 0.f); o1 = fmaxf(o1, 0.f); }
  if (POSTSCALE) { o0 *= wd; o1 *= wd; }
  if (OUTHALF) {
    *(__half2*)((__half*)out + (size_t)gw * D + l * 2) = __floats2half2_rn(o0, o1);
  } else {
    *(float2*)((float*)out + (size_t)gw * D + l * 2) = make_float2(o0, o1);
  }
}

#define DEF_AGG(NAME, D, RELU, HASBIAS, POSTSCALE, OUTHALF)                                \
  __global__ void NAME(const __half* __restrict__ hs, const int* __restrict__ row_ptr,     \
                       const int* __restrict__ csr_src, const float* __restrict__ isd,     \
                       const float* __restrict__ bias, void* __restrict__ out, int n) {    \
    agg_body<D, RELU, HASBIAS, POSTSCALE, OUTHALF>(hs, row_ptr, csr_src, isd, bias, out, n); \
  }
DEF_AGG(agg1_d128_biasrelu_f16, 128, true, true, false, true)
DEF_AGG(agg2_d64_bias_ps_f16, 64, false, true, true, true)
DEF_AGG(agg3_d64_plain_f16, 64, false, false, false, true)
DEF_AGG(agg4_d128_bias_f32, 128, false, true, false, false)

static inline size_t align_up(size_t x, size_t a) { return (x + a - 1) & ~(a - 1); }

extern "C" void kernel_launch(void* const* d_in, const int* in_sizes, int n_in,
                              void* d_out, int out_size, void* d_ws, size_t ws_size,
                              hipStream_t stream) {
  const float* X  = (const float*)d_in[0];
  const float* W1 = (const float*)d_in[1];
  const float* b1 = (const float*)d_in[2];
  const float* W2 = (const float*)d_in[3];
  const float* b2 = (const float*)d_in[4];
  const float* W3 = (const float*)d_in[5];
  const float* b3 = (const float*)d_in[6];
  const float* W4 = (const float*)d_in[7];
  const float* b4 = (const float*)d_in[8];
  const int*   ei = (const int*)d_in[9];

  const int N = in_sizes[0] / 128;
  const int E = in_sizes[9] / 2;
  const int* src = ei;
  const int* dst = ei + E;
  float* OUT = (float*)d_out;

  char* ws = (char*)d_ws;
  size_t off = 0;
  auto alloc = [&](size_t bytes) { void* p = ws + off; off = align_up(off + bytes, 256); return p; };
  int*    counts  = (int*)alloc((size_t)N * 4);
  int*    row_ptr = (int*)alloc(((size_t)N + 1) * 4);
  float*  isd     = (float*)alloc((size_t)N * 4);
  int*    csr_src = (int*)alloc((size_t)E * 4);
  int*    blksum  = (int*)alloc(1024 * 4);
  int*    blkoff  = (int*)alloc(1024 * 4);
  __half* B1      = (__half*)alloc((size_t)N * 128 * 2);
  __half* B2      = (__half*)alloc((size_t)N * 128 * 2);
  __half* Fa = B1;                   // N x 64 f16 view (also G)
  __half* Fb = B1 + (size_t)N * 64;  // N x 64 f16 view

  hipMemsetAsync(counts, 0, (size_t)N * 4, stream);

  int eb = (E + 255) / 256;
  int nb = (N + 255) / 256;  // 391 for N=100k, must be <= 1024 for scan2
  hist_kernel<<<eb, 256, 0, stream>>>(dst, counts, E);
  isd_kernel<<<nb, 256, 0, stream>>>(counts, isd, N);
  scan1_kernel<<<nb, 256, 0, stream>>>(counts, row_ptr, blksum, N);
  scan2_kernel<<<1, 1024, 0, stream>>>(blksum, blkoff, row_ptr, nb, N);
  scan3_kernel<<<nb, 256, 0, stream>>>(row_ptr, blkoff, N);
  fill_kernel<<<eb, 256, 0, stream>>>(src, dst, row_ptr, counts, csr_src, E);

  const int gm = (N + 63) / 64;
  const int ab128 = (int)(((size_t)N * 64 + 255) / 256);
  const int ab64  = (int)(((size_t)N * 32 + 255) / 256);

  // L1: B1 = f16(isd*(X@W1)) ; B2 = z1 = f16(relu(P'+b1))
  gemm1_mfma_k128_n128<<<dim3(gm, 2), 256, 0, stream>>>(X, W1, isd, B1, N);
  agg1_d128_biasrelu_f16<<<ab128, 256, 0, stream>>>(B1, row_ptr, csr_src, isd, b1, B2, N);
  // L2: Fa = f16(isd*(z1@W2)) ; Fb = f16(isd*(P'+b2))
  gemm2_mfma_k128_n64<<<dim3(gm, 1), 256, 0, stream>>>(B2, W2, isd, Fa, N);
  agg2_d64_bias_ps_f16<<<ab64, 256, 0, stream>>>(Fa, row_ptr, csr_src, isd, b2, Fb, N);
  // L3: G(=Fa) = f16(P(z2)) ; B2 = z3 = f16(relu(G@W3+b3))
  agg3_d64_plain_f16<<<ab64, 256, 0, stream>>>(Fb, row_ptr, csr_src, isd, nullptr, Fa, N);
  gemm3_mfma_k64_n128<<<dim3(gm, 2), 256, 0, stream>>>(Fa, W3, b3, B2, N);
  // L4: B1 = f16(isd*(z3@W4)) ; out = P'+b4 -> OUT (fp32)
  gemm4_mfma_k128_n128<<<dim3(gm, 2), 256, 0, stream>>>(B2, W4, isd, B1, N);
  agg4_d128_bias_f32<<<ab128, 256, 0, stream>>>(B1, row_ptr, csr_src, isd, b4, OUT, N);
}

// Round 8
// 424.407 us; speedup vs baseline: 1.7560x; 1.0922x over previous
//
#include <hip/hip_runtime.h>
#include <hip/hip_fp16.h>

typedef _Float16 f16x8 __attribute__((ext_vector_type(8)));
typedef float f32x4 __attribute__((ext_vector_type(4)));

#define CHUNK 4096
#define BSHIFT 9  // 512 dsts per bucket -> NB = ceil(N/512) = 196 <= 256

// ---------------------------------------------------------------------------
// 4-layer GCN, all intermediates fp16 (fp32 accumulate everywhere):
//   P(Y)_d = isd_d * (sum_{e:dst=d} Ys_src + Ys_d)  with Ys = isd*Y (pre-scaled)
// CSR build is 3-phase bucketed to kill the 16x scatter-write amplification
// (r7: fill_kernel WRITE_SIZE=107MB for 6.4MB of payload, 120us).
// ---------------------------------------------------------------------------

// Phase A: per-dst degree hist (global atomics) + per-bucket count (LDS-staged)
static __global__ void hist_bucket_kernel(const int* __restrict__ dst, int* __restrict__ counts,
                                          int* __restrict__ bucket_cnt, int E, int NB) {
  __shared__ int lh[256];
  int t = threadIdx.x;
  lh[t] = 0;
  __syncthreads();
  int base = blockIdx.x * CHUNK;
  int end = min(base + CHUNK, E);
  for (int i = base + t; i < end; i += 256) {
    int d = dst[i];
    atomicAdd(&counts[d], 1);
    atomicAdd(&lh[d >> BSHIFT], 1);
  }
  __syncthreads();
  if (t < NB && lh[t]) atomicAdd(&bucket_cnt[t], lh[t]);
}

static __global__ void isd_kernel(const int* __restrict__ counts, float* __restrict__ isd, int n) {
  int i = blockIdx.x * blockDim.x + threadIdx.x;
  if (i < n) isd[i] = rsqrtf((float)counts[i] + 1.0f);
}

// 3-pass exclusive scan for row_ptr
static __global__ void scan1_kernel(const int* __restrict__ counts, int* __restrict__ row_ptr,
                                    int* __restrict__ blksum, int n) {
  __shared__ int sh[256];
  int i = blockIdx.x * 256 + threadIdx.x;
  int v = (i < n) ? counts[i] : 0;
  sh[threadIdx.x] = v;
  __syncthreads();
  for (int off = 1; off < 256; off <<= 1) {
    int t = ((int)threadIdx.x >= off) ? sh[threadIdx.x - off] : 0;
    __syncthreads();
    sh[threadIdx.x] += t;
    __syncthreads();
  }
  if (i < n) row_ptr[i] = sh[threadIdx.x] - v;
  if (threadIdx.x == 255) blksum[blockIdx.x] = sh[255];
}

static __global__ void scan2_kernel(const int* __restrict__ blksum, int* __restrict__ blkoff,
                                    int* __restrict__ row_ptr, int nb, int n) {
  __shared__ int sh[1024];
  int v = ((int)threadIdx.x < nb) ? blksum[threadIdx.x] : 0;
  sh[threadIdx.x] = v;
  __syncthreads();
  for (int off = 1; off < 1024; off <<= 1) {
    int t = ((int)threadIdx.x >= off) ? sh[threadIdx.x - off] : 0;
    __syncthreads();
    sh[threadIdx.x] += t;
    __syncthreads();
  }
  if ((int)threadIdx.x < nb) blkoff[threadIdx.x] = sh[threadIdx.x] - v;
  if ((int)threadIdx.x == nb - 1) row_ptr[n] = sh[threadIdx.x];
}

static __global__ void scan3_kernel(int* __restrict__ row_ptr, const int* __restrict__ blkoff, int n) {
  int i = blockIdx.x * 256 + threadIdx.x;
  if (i < n) row_ptr[i] += blkoff[blockIdx.x];
}

// bucket scan: NB <= 256, one block; also init bucket_cur
static __global__ void bscan_kernel(const int* __restrict__ bucket_cnt, int* __restrict__ bucket_off,
                                    int* __restrict__ bucket_cur, int NB) {
  __shared__ int sh[256];
  int t = threadIdx.x;
  int v = (t < NB) ? bucket_cnt[t] : 0;
  sh[t] = v;
  __syncthreads();
  for (int off = 1; off < 256; off <<= 1) {
    int x = (t >= off) ? sh[t - off] : 0;
    __syncthreads();
    sh[t] += x;
    __syncthreads();
  }
  if (t < NB) {
    bucket_off[t] = sh[t] - v;
    bucket_cur[t] = sh[t] - v;
  }
}

// Phase B: bin edges into bucket runs. Per-chunk LDS hist -> reserve global
// run (1 atomic per bucket per block) -> scatter (src,dst) pairs into runs.
static __global__ void binpass_kernel(const int* __restrict__ src, const int* __restrict__ dst,
                                      int* __restrict__ bucket_cur, int2* __restrict__ pairs,
                                      int E, int NB) {
  __shared__ int lh[256], lbase[256], lcur[256];
  int t = threadIdx.x;
  lh[t] = 0;
  __syncthreads();
  int base = blockIdx.x * CHUNK;
  int end = min(base + CHUNK, E);
  for (int i = base + t; i < end; i += 256)
    atomicAdd(&lh[dst[i] >> BSHIFT], 1);
  __syncthreads();
  if (t < NB && lh[t]) lbase[t] = atomicAdd(&bucket_cur[t], lh[t]);
  lcur[t] = 0;
  __syncthreads();
  for (int i = base + t; i < end; i += 256) {
    int d = dst[i];
    int b = d >> BSHIFT;
    int p = lbase[b] + atomicAdd(&lcur[b], 1);
    pairs[p] = make_int2(src[i], d);
  }
}

// Phase C: one block per bucket; scatter within the bucket's ~32KB csr span
// (single-XCD writer -> full-line writebacks). counts used as per-dst cursor.
static __global__ void fillpass_kernel(const int2* __restrict__ pairs, const int* __restrict__ bucket_off,
                                       const int* __restrict__ bucket_cnt, const int* __restrict__ row_ptr,
                                       int* __restrict__ counts, int* __restrict__ csr_src) {
  int b = blockIdx.x;
  int beg = bucket_off[b], end = beg + bucket_cnt[b];
  for (int i = beg + (int)threadIdx.x; i < end; i += 256) {
    int2 e = pairs[i];
    int k = atomicSub(&counts[e.y], 1) - 1;
    csr_src[row_ptr[e.y] + k] = e.x;
  }
}

// ---------------------------------------------------------------------------
// MFMA GEMM: H[n,NOUT](f16) = epi(X[n,K] @ W[K,NOUT]) ; fp32 accumulate.
// 64x64 tile, 4 waves, 2x2 16x16x32 frags per wave.
// ---------------------------------------------------------------------------
template<int K, int NOUT, bool AHALF, int EPI>
__device__ __forceinline__ void gemm_mfma_body(const void* __restrict__ Xin,
                                               const float* __restrict__ W,
                                               const float* __restrict__ aux,
                                               __half* __restrict__ H, int n) {
  __shared__ _Float16 ah[64][K + 8];
  __shared__ _Float16 bh[64][K + 8];
  const int tid = threadIdx.x;
  const int bm = blockIdx.x * 64;
  const int bc = blockIdx.y * 64;

  if (AHALF) {
    const __half* Xh = (const __half*)Xin;
    for (int i = tid; i < 64 * (K / 8); i += 256) {
      int r = i / (K / 8), c8 = i % (K / 8);
      int gr = bm + r;
      f16x8 v = {};
      if (gr < n) v = *(const f16x8*)&Xh[(size_t)gr * K + c8 * 8];
      *(f16x8*)&ah[r][c8 * 8] = v;
    }
  } else {
    const float* Xf = (const float*)Xin;
    for (int i = tid; i < 64 * (K / 8); i += 256) {
      int r = i / (K / 8), c8 = i % (K / 8);
      int gr = bm + r;
      f16x8 v = {};
      if (gr < n) {
        float4 a = *(const float4*)&Xf[(size_t)gr * K + c8 * 8];
        float4 b = *(const float4*)&Xf[(size_t)gr * K + c8 * 8 + 4];
        v[0] = (_Float16)a.x; v[1] = (_Float16)a.y; v[2] = (_Float16)a.z; v[3] = (_Float16)a.w;
        v[4] = (_Float16)b.x; v[5] = (_Float16)b.y; v[6] = (_Float16)b.z; v[7] = (_Float16)b.w;
      }
      *(f16x8*)&ah[r][c8 * 8] = v;
    }
  }
  {
    const int nn = tid & 63;
    const int kq = tid >> 6;
    constexpr int KT = K / 4;
#pragma unroll
    for (int k8 = 0; k8 < KT; k8 += 8) {
      int k0 = kq * KT + k8;
      f16x8 v;
#pragma unroll
      for (int j = 0; j < 8; ++j)
        v[j] = (_Float16)W[(size_t)(k0 + j) * NOUT + bc + nn];
      *(f16x8*)&bh[nn][k0] = v;
    }
  }
  __syncthreads();

  const int lane = tid & 63;
  const int wid = tid >> 6;
  const int wm = (wid >> 1) * 32;
  const int wn = (wid & 1) * 32;
  const int lr = lane & 15;
  const int lk = (lane >> 4) * 8;

  f32x4 acc[2][2] = {};
#pragma unroll
  for (int ks = 0; ks < K; ks += 32) {
    f16x8 a0 = *(const f16x8*)&ah[wm + lr][ks + lk];
    f16x8 a1 = *(const f16x8*)&ah[wm + 16 + lr][ks + lk];
    f16x8 b0 = *(const f16x8*)&bh[wn + lr][ks + lk];
    f16x8 b1 = *(const f16x8*)&bh[wn + 16 + lr][ks + lk];
    acc[0][0] = __builtin_amdgcn_mfma_f32_16x16x32_f16(a0, b0, acc[0][0], 0, 0, 0);
    acc[0][1] = __builtin_amdgcn_mfma_f32_16x16x32_f16(a0, b1, acc[0][1], 0, 0, 0);
    acc[1][0] = __builtin_amdgcn_mfma_f32_16x16x32_f16(a1, b0, acc[1][0], 0, 0, 0);
    acc[1][1] = __builtin_amdgcn_mfma_f32_16x16x32_f16(a1, b1, acc[1][1], 0, 0, 0);
  }

  float bcol0 = 0.f, bcol1 = 0.f;
  if (EPI == 1) {
    bcol0 = aux[bc + wn + lr];
    bcol1 = aux[bc + wn + 16 + lr];
  }
  const int rgrp = (lane >> 4) * 4;
#pragma unroll
  for (int tm = 0; tm < 2; ++tm) {
    int rb = bm + wm + tm * 16 + rgrp;
#pragma unroll
    for (int r = 0; r < 4; ++r) {
      int row = rb + r;
      if (row >= n) continue;
      float s = (EPI == 0) ? aux[row] : 0.f;
#pragma unroll
      for (int tn = 0; tn < 2; ++tn) {
        int col = bc + wn + tn * 16 + lr;
        float v = acc[tm][tn][r];
        if (EPI == 0) v *= s;
        else v = fmaxf(v + (tn ? bcol1 : bcol0), 0.f);
        H[(size_t)row * NOUT + col] = __float2half(v);
      }
    }
  }
}

#define DEF_GEMM(NAME, K, NOUT, AHALF, EPI)                                              \
  __global__ __launch_bounds__(256, 2) void NAME(const void* __restrict__ X,             \
                                                 const float* __restrict__ W,            \
                                                 const float* __restrict__ aux,          \
                                                 __half* __restrict__ H, int n) {        \
    gemm_mfma_body<K, NOUT, AHALF, EPI>(X, W, aux, H, n);                                \
  }
DEF_GEMM(gemm1_mfma_k128_n128, 128, 128, false, 0)
DEF_GEMM(gemm2_mfma_k128_n64, 128, 64, true, 0)
DEF_GEMM(gemm3_mfma_k64_n128, 64, 128, true, 1)
DEF_GEMM(gemm4_mfma_k128_n128, 128, 128, true, 0)

// ---------------------------------------------------------------------------
// Aggregation over fp16 pre-scaled rows (fp32 accumulate).
// ---------------------------------------------------------------------------
template<int D, bool RELU, bool HASBIAS, bool POSTSCALE, bool OUTHALF>
__device__ __forceinline__ void agg_body(const __half* __restrict__ hs, const int* __restrict__ row_ptr,
                                         const int* __restrict__ csr_src, const float* __restrict__ isd,
                                         const float* __restrict__ bias, void* __restrict__ out, int n) {
  int gt = blockIdx.x * blockDim.x + threadIdx.x;
  int gw, l;
  if (D == 128) {
    gw = gt >> 6;
    l = threadIdx.x & 63;
  } else {
    gw = (gt >> 6) * 2 + ((threadIdx.x >> 5) & 1);
    l = threadIdx.x & 31;
  }
  if (gw >= n) return;

  float wd = isd[gw];
  float2 hv = __half22float2(*(const __half2*)(hs + (size_t)gw * D + l * 2));
  float2 bv = make_float2(0.f, 0.f);
  if (HASBIAS) bv = *(const float2*)(bias + l * 2);

  int beg = row_ptr[gw], end = row_ptr[gw + 1];
  float acc0 = 0.f, acc1 = 0.f;

  int e = beg;
  int s0 = 0, s1 = 0, s2 = 0, s3 = 0;
  if (e + 4 <= end) {
    s0 = csr_src[e + 0]; s1 = csr_src[e + 1];
    s2 = csr_src[e + 2]; s3 = csr_src[e + 3];
  }
  while (e + 4 <= end) {
    float2 v0 = __half22float2(*(const __half2*)(hs + (size_t)s0 * D + l * 2));
    float2 v1 = __half22float2(*(const __half2*)(hs + (size_t)s1 * D + l * 2));
    float2 v2 = __half22float2(*(const __half2*)(hs + (size_t)s2 * D + l * 2));
    float2 v3 = __half22float2(*(const __half2*)(hs + (size_t)s3 * D + l * 2));
    int en = e + 4;
    if (en + 4 <= end) {
      s0 = csr_src[en + 0]; s1 = csr_src[en + 1];
      s2 = csr_src[en + 2]; s3 = csr_src[en + 3];
    }
    acc0 += (v0.x + v1.x) + (v2.x + v3.x);
    acc1 += (v0.y + v1.y) + (v2.y + v3.y);
    e = en;
  }
  for (; e < end; ++e) {
    int s = csr_src[e];
    float2 v = __half22float2(*(const __half2*)(hs + (size_t)s * D + l * 2));
    acc0 += v.x;
    acc1 += v.y;
  }

  float o0 = wd * (acc0 + hv.x);
  float o1 = wd * (acc1 + hv.y);
  if (HASBIAS) { o0 += bv.x; o1 += bv.y; }
  if (RELU) { o0 = fmaxf(o0, 0.f); o1 = fmaxf(o1, 0.f); }
  if (POSTSCALE) { o0 *= wd; o1 *= wd; }
  if (OUTHALF) {
    *(__half2*)((__half*)out + (size_t)gw * D + l * 2) = __floats2half2_rn(o0, o1);
  } else {
    *(float2*)((float*)out + (size_t)gw * D + l * 2) = make_float2(o0, o1);
  }
}

#define DEF_AGG(NAME, D, RELU, HASBIAS, POSTSCALE, OUTHALF)                                \
  __global__ void NAME(const __half* __restrict__ hs, const int* __restrict__ row_ptr,     \
                       const int* __restrict__ csr_src, const float* __restrict__ isd,     \
                       const float* __restrict__ bias, void* __restrict__ out, int n) {    \
    agg_body<D, RELU, HASBIAS, POSTSCALE, OUTHALF>(hs, row_ptr, csr_src, isd, bias, out, n); \
  }
DEF_AGG(agg1_d128_biasrelu_f16, 128, true, true, false, true)
DEF_AGG(agg2_d64_bias_ps_f16, 64, false, true, true, true)
DEF_AGG(agg3_d64_plain_f16, 64, false, false, false, true)
DEF_AGG(agg4_d128_bias_f32, 128, false, true, false, false)

static inline size_t align_up(size_t x, size_t a) { return (x + a - 1) & ~(a - 1); }

extern "C" void kernel_launch(void* const* d_in, const int* in_sizes, int n_in,
                              void* d_out, int out_size, void* d_ws, size_t ws_size,
                              hipStream_t stream) {
  const float* X  = (const float*)d_in[0];
  const float* W1 = (const float*)d_in[1];
  const float* b1 = (const float*)d_in[2];
  const float* W2 = (const float*)d_in[3];
  const float* b2 = (const float*)d_in[4];
  const float* W3 = (const float*)d_in[5];
  const float* b3 = (const float*)d_in[6];
  const float* W4 = (const float*)d_in[7];
  const float* b4 = (const float*)d_in[8];
  const int*   ei = (const int*)d_in[9];

  const int N = in_sizes[0] / 128;
  const int E = in_sizes[9] / 2;
  const int* src = ei;
  const int* dst = ei + E;
  float* OUT = (float*)d_out;

  const int NB = (N + (1 << BSHIFT) - 1) >> BSHIFT;  // 196 for N=100k (must be <=256)
  const int NCH = (E + CHUNK - 1) / CHUNK;

  char* ws = (char*)d_ws;
  size_t off = 0;
  auto alloc = [&](size_t bytes) { void* p = ws + off; off = align_up(off + bytes, 256); return p; };
  int*    counts     = (int*)alloc((size_t)N * 4);
  int*    row_ptr    = (int*)alloc(((size_t)N + 1) * 4);
  float*  isd        = (float*)alloc((size_t)N * 4);
  int*    csr_src    = (int*)alloc((size_t)E * 4);
  int*    blksum     = (int*)alloc(1024 * 4);
  int*    blkoff     = (int*)alloc(1024 * 4);
  int*    bucket_cnt = (int*)alloc(256 * 4);
  int*    bucket_off = (int*)alloc(256 * 4);
  int*    bucket_cur = (int*)alloc(256 * 4);
  __half* B1         = (__half*)alloc((size_t)N * 128 * 2);
  __half* B2         = (__half*)alloc((size_t)N * 128 * 2);
  __half* Fa = B1;
  __half* Fb = B1 + (size_t)N * 64;
  int2*   pairs = (int2*)B1;  // 12.8MB, dead before gemm1 writes B1

  hipMemsetAsync(counts, 0, (size_t)N * 4, stream);
  hipMemsetAsync(bucket_cnt, 0, 256 * 4, stream);

  int nb = (N + 255) / 256;  // 391 for N=100k, must be <= 1024 for scan2
  hist_bucket_kernel<<<NCH, 256, 0, stream>>>(dst, counts, bucket_cnt, E, NB);
  isd_kernel<<<nb, 256, 0, stream>>>(counts, isd, N);
  scan1_kernel<<<nb, 256, 0, stream>>>(counts, row_ptr, blksum, N);
  scan2_kernel<<<1, 1024, 0, stream>>>(blksum, blkoff, row_ptr, nb, N);
  scan3_kernel<<<nb, 256, 0, stream>>>(row_ptr, blkoff, N);
  bscan_kernel<<<1, 256, 0, stream>>>(bucket_cnt, bucket_off, bucket_cur, NB);
  binpass_kernel<<<NCH, 256, 0, stream>>>(src, dst, bucket_cur, pairs, E, NB);
  fillpass_kernel<<<NB, 256, 0, stream>>>(pairs, bucket_off, bucket_cnt, row_ptr, counts, csr_src);

  const int gm = (N + 63) / 64;
  const int ab128 = (int)(((size_t)N * 64 + 255) / 256);
  const int ab64  = (int)(((size_t)N * 32 + 255) / 256);

  // L1: B1 = f16(isd*(X@W1)) ; B2 = z1 = f16(relu(P'+b1))
  gemm1_mfma_k128_n128<<<dim3(gm, 2), 256, 0, stream>>>(X, W1, isd, B1, N);
  agg1_d128_biasrelu_f16<<<ab128, 256, 0, stream>>>(B1, row_ptr, csr_src, isd, b1, B2, N);
  // L2: Fa = f16(isd*(z1@W2)) ; Fb = f16(isd*(P'+b2))
  gemm2_mfma_k128_n64<<<dim3(gm, 1), 256, 0, stream>>>(B2, W2, isd, Fa, N);
  agg2_d64_bias_ps_f16<<<ab64, 256, 0, stream>>>(Fa, row_ptr, csr_src, isd, b2, Fb, N);
  // L3: G(=Fa) = f16(P(z2)) ; B2 = z3 = f16(relu(G@W3+b3))
  agg3_d64_plain_f16<<<ab64, 256, 0, stream>>>(Fb, row_ptr, csr_src, isd, nullptr, Fa, N);
  gemm3_mfma_k64_n128<<<dim3(gm, 2), 256, 0, stream>>>(Fa, W3, b3, B2, N);
  // L4: B1 = f16(isd*(z3@W4)) ; out = P'+b4 -> OUT (fp32)
  gemm4_mfma_k128_n128<<<dim3(gm, 2), 256, 0, stream>>>(B2, W4, isd, B1, N);
  agg4_d128_bias_f32<<<ab128, 256, 0, stream>>>(B1, row_ptr, csr_src, isd, b4, OUT, N);
}

// Round 9
// 333.902 us; speedup vs baseline: 2.2320x; 1.2711x over previous
//
#include <hip/hip_runtime.h>
#include <hip/hip_fp16.h>

typedef _Float16 f16x8 __attribute__((ext_vector_type(8)));
typedef float f32x4 __attribute__((ext_vector_type(4)));

#define CHUNK 2048
#define BSHIFT 9          // 512 dsts per bucket
#define CAP 12288         // bucket run capacity; E*512/N ~= 8192 expected (~45 sigma margin)

// ---------------------------------------------------------------------------
// 4-layer GCN, all intermediates fp16 (fp32 accumulate everywhere):
//   P(Y)_d = isd_d * (sum_{e:dst=d} Ys_src + Ys_d)  with Ys = isd*Y (pre-scaled)
// CSR build: bucket-scatter (fixed-cap runs) + per-bucket LDS hist/scan/fill.
// No per-dst global atomics anywhere (r8: 1.6M random atomic RMWs = 70us).
// ---------------------------------------------------------------------------

// bin edges into fixed-capacity bucket runs; 1 global atomic per (block,bucket)
static __global__ void binpass_kernel(const int* __restrict__ src, const int* __restrict__ dst,
                                      int* __restrict__ bucket_cur, int2* __restrict__ pairs,
                                      int E, int NB) {
  __shared__ int lh[256], lbase[256], lcur[256];
  int t = threadIdx.x;
  lh[t] = 0;
  __syncthreads();
  int base = blockIdx.x * CHUNK;
  int end = min(base + CHUNK, E);
  for (int i = base + t; i < end; i += 256)
    atomicAdd(&lh[dst[i] >> BSHIFT], 1);
  __syncthreads();
  if (t < NB && lh[t]) lbase[t] = atomicAdd(&bucket_cur[t], lh[t]);
  lcur[t] = 0;
  __syncthreads();
  for (int i = base + t; i < end; i += 256) {
    int s = src[i], d = dst[i];
    int b = d >> BSHIFT;
    int p = lbase[b] + atomicAdd(&lcur[b], 1);
    if (p < CAP) pairs[(size_t)b * CAP + p] = make_int2(s, d);
  }
}

// exclusive scan of bucket counts -> global edge offsets; row_ptr[n] = E
static __global__ void bedge_scan_kernel(const int* __restrict__ bucket_cur,
                                         int* __restrict__ bucket_base,
                                         int* __restrict__ row_ptr, int NB, int n, int E) {
  __shared__ int sh[256];
  int t = threadIdx.x;
  int v = (t < NB) ? bucket_cur[t] : 0;
  sh[t] = v;
  __syncthreads();
  for (int off = 1; off < 256; off <<= 1) {
    int x = (t >= off) ? sh[t - off] : 0;
    __syncthreads();
    sh[t] += x;
    __syncthreads();
  }
  if (t < NB) bucket_base[t] = sh[t] - v;
  if (t == 0) row_ptr[n] = E;
}

// one block per bucket: LDS degree hist -> LDS scan -> coalesced row_ptr/isd
// writes -> LDS-cursor CSR fill within the bucket's contiguous span.
static __global__ void bucket_work_kernel(const int2* __restrict__ pairs,
                                          const int* __restrict__ bucket_cur,
                                          const int* __restrict__ bucket_base,
                                          float* __restrict__ isd, int* __restrict__ row_ptr,
                                          int* __restrict__ csr_src, int n) {
  __shared__ int lcnt[512];
  __shared__ int lcur[512];
  __shared__ int s2[256];
  int b = blockIdx.x;
  int t = threadIdx.x;
  int d0 = b << BSHIFT;
  int cnt = bucket_cur[b];
  int base = bucket_base[b];
  const int2* bp = pairs + (size_t)b * CAP;
  lcnt[t] = 0;
  lcnt[t + 256] = 0;
  __syncthreads();
  for (int i = t; i < cnt; i += 256)
    atomicAdd(&lcnt[bp[i].y - d0], 1);
  __syncthreads();
  int a0 = lcnt[2 * t], a1 = lcnt[2 * t + 1];
  s2[t] = a0 + a1;
  __syncthreads();
  for (int off = 1; off < 256; off <<= 1) {
    int x = (t >= off) ? s2[t - off] : 0;
    __syncthreads();
    s2[t] += x;
    __syncthreads();
  }
  int excl = s2[t] - (a0 + a1);
  int d = d0 + 2 * t;
  if (d < n)     { row_ptr[d]     = base + excl;      isd[d]     = rsqrtf((float)a0 + 1.0f); }
  if (d + 1 < n) { row_ptr[d + 1] = base + excl + a0; isd[d + 1] = rsqrtf((float)a1 + 1.0f); }
  lcur[2 * t] = excl;
  lcur[2 * t + 1] = excl + a0;
  __syncthreads();
  for (int i = t; i < cnt; i += 256) {
    int2 e = bp[i];
    int p = atomicAdd(&lcur[e.y - d0], 1);
    csr_src[base + p] = e.x;
  }
}

// ---------------------------------------------------------------------------
// MFMA GEMM: H[n,NOUT](f16) = epi(X[n,K] @ W[K,NOUT]) ; fp32 accumulate.
// 64x64 tile, 4 waves, 2x2 16x16x32 frags per wave.
// ---------------------------------------------------------------------------
template<int K, int NOUT, bool AHALF, int EPI>
__device__ __forceinline__ void gemm_mfma_body(const void* __restrict__ Xin,
                                               const float* __restrict__ W,
                                               const float* __restrict__ aux,
                                               __half* __restrict__ H, int n) {
  __shared__ _Float16 ah[64][K + 8];
  __shared__ _Float16 bh[64][K + 8];
  const int tid = threadIdx.x;
  const int bm = blockIdx.x * 64;
  const int bc = blockIdx.y * 64;

  if (AHALF) {
    const __half* Xh = (const __half*)Xin;
    for (int i = tid; i < 64 * (K / 8); i += 256) {
      int r = i / (K / 8), c8 = i % (K / 8);
      int gr = bm + r;
      f16x8 v = {};
      if (gr < n) v = *(const f16x8*)&Xh[(size_t)gr * K + c8 * 8];
      *(f16x8*)&ah[r][c8 * 8] = v;
    }
  } else {
    const float* Xf = (const float*)Xin;
    for (int i = tid; i < 64 * (K / 8); i += 256) {
      int r = i / (K / 8), c8 = i % (K / 8);
      int gr = bm + r;
      f16x8 v = {};
      if (gr < n) {
        float4 a = *(const float4*)&Xf[(size_t)gr * K + c8 * 8];
        float4 b = *(const float4*)&Xf[(size_t)gr * K + c8 * 8 + 4];
        v[0] = (_Float16)a.x; v[1] = (_Float16)a.y; v[2] = (_Float16)a.z; v[3] = (_Float16)a.w;
        v[4] = (_Float16)b.x; v[5] = (_Float16)b.y; v[6] = (_Float16)b.z; v[7] = (_Float16)b.w;
      }
      *(f16x8*)&ah[r][c8 * 8] = v;
    }
  }
  {
    const int nn = tid & 63;
    const int kq = tid >> 6;
    constexpr int KT = K / 4;
#pragma unroll
    for (int k8 = 0; k8 < KT; k8 += 8) {
      int k0 = kq * KT + k8;
      f16x8 v;
#pragma unroll
      for (int j = 0; j < 8; ++j)
        v[j] = (_Float16)W[(size_t)(k0 + j) * NOUT + bc + nn];
      *(f16x8*)&bh[nn][k0] = v;
    }
  }
  __syncthreads();

  const int lane = tid & 63;
  const int wid = tid >> 6;
  const int wm = (wid >> 1) * 32;
  const int wn = (wid & 1) * 32;
  const int lr = lane & 15;
  const int lk = (lane >> 4) * 8;

  f32x4 acc[2][2] = {};
#pragma unroll
  for (int ks = 0; ks < K; ks += 32) {
    f16x8 a0 = *(const f16x8*)&ah[wm + lr][ks + lk];
    f16x8 a1 = *(const f16x8*)&ah[wm + 16 + lr][ks + lk];
    f16x8 b0 = *(const f16x8*)&bh[wn + lr][ks + lk];
    f16x8 b1 = *(const f16x8*)&bh[wn + 16 + lr][ks + lk];
    acc[0][0] = __builtin_amdgcn_mfma_f32_16x16x32_f16(a0, b0, acc[0][0], 0, 0, 0);
    acc[0][1] = __builtin_amdgcn_mfma_f32_16x16x32_f16(a0, b1, acc[0][1], 0, 0, 0);
    acc[1][0] = __builtin_amdgcn_mfma_f32_16x16x32_f16(a1, b0, acc[1][0], 0, 0, 0);
    acc[1][1] = __builtin_amdgcn_mfma_f32_16x16x32_f16(a1, b1, acc[1][1], 0, 0, 0);
  }

  float bcol0 = 0.f, bcol1 = 0.f;
  if (EPI == 1) {
    bcol0 = aux[bc + wn + lr];
    bcol1 = aux[bc + wn + 16 + lr];
  }
  const int rgrp = (lane >> 4) * 4;
#pragma unroll
  for (int tm = 0; tm < 2; ++tm) {
    int rb = bm + wm + tm * 16 + rgrp;
#pragma unroll
    for (int r = 0; r < 4; ++r) {
      int row = rb + r;
      if (row >= n) continue;
      float s = (EPI == 0) ? aux[row] : 0.f;
#pragma unroll
      for (int tn = 0; tn < 2; ++tn) {
        int col = bc + wn + tn * 16 + lr;
        float v = acc[tm][tn][r];
        if (EPI == 0) v *= s;
        else v = fmaxf(v + (tn ? bcol1 : bcol0), 0.f);
        H[(size_t)row * NOUT + col] = __float2half(v);
      }
    }
  }
}

#define DEF_GEMM(NAME, K, NOUT, AHALF, EPI)                                              \
  __global__ __launch_bounds__(256, 2) void NAME(const void* __restrict__ X,             \
                                                 const float* __restrict__ W,            \
                                                 const float* __restrict__ aux,          \
                                                 __half* __restrict__ H, int n) {        \
    gemm_mfma_body<K, NOUT, AHALF, EPI>(X, W, aux, H, n);                                \
  }
DEF_GEMM(gemm1_mfma_k128_n128, 128, 128, false, 0)
DEF_GEMM(gemm2_mfma_k128_n64, 128, 64, true, 0)
DEF_GEMM(gemm3_mfma_k64_n128, 64, 128, true, 1)
DEF_GEMM(gemm4_mfma_k128_n128, 128, 128, true, 0)

// ---------------------------------------------------------------------------
// Aggregation over fp16 pre-scaled rows (fp32 accumulate).
// ---------------------------------------------------------------------------
template<int D, bool RELU, bool HASBIAS, bool POSTSCALE, bool OUTHALF>
__device__ __forceinline__ void agg_body(const __half* __restrict__ hs, const int* __restrict__ row_ptr,
                                         const int* __restrict__ csr_src, const float* __restrict__ isd,
                                         const float* __restrict__ bias, void* __restrict__ out, int n) {
  int gt = blockIdx.x * blockDim.x + threadIdx.x;
  int gw, l;
  if (D == 128) {
    gw = gt >> 6;
    l = threadIdx.x & 63;
  } else {
    gw = (gt >> 6) * 2 + ((threadIdx.x >> 5) & 1);
    l = threadIdx.x & 31;
  }
  if (gw >= n) return;

  float wd = isd[gw];
  float2 hv = __half22float2(*(const __half2*)(hs + (size_t)gw * D + l * 2));
  float2 bv = make_float2(0.f, 0.f);
  if (HASBIAS) bv = *(const float2*)(bias + l * 2);

  int beg = row_ptr[gw], end = row_ptr[gw + 1];
  float acc0 = 0.f, acc1 = 0.f;

  int e = beg;
  int s0 = 0, s1 = 0, s2 = 0, s3 = 0;
  if (e + 4 <= end) {
    s0 = csr_src[e + 0]; s1 = csr_src[e + 1];
    s2 = csr_src[e + 2]; s3 = csr_src[e + 3];
  }
  while (e + 4 <= end) {
    float2 v0 = __half22float2(*(const __half2*)(hs + (size_t)s0 * D + l * 2));
    float2 v1 = __half22float2(*(const __half2*)(hs + (size_t)s1 * D + l * 2));
    float2 v2 = __half22float2(*(const __half2*)(hs + (size_t)s2 * D + l * 2));
    float2 v3 = __half22float2(*(const __half2*)(hs + (size_t)s3 * D + l * 2));
    int en = e + 4;
    if (en + 4 <= end) {
      s0 = csr_src[en + 0]; s1 = csr_src[en + 1];
      s2 = csr_src[en + 2]; s3 = csr_src[en + 3];
    }
    acc0 += (v0.x + v1.x) + (v2.x + v3.x);
    acc1 += (v0.y + v1.y) + (v2.y + v3.y);
    e = en;
  }
  for (; e < end; ++e) {
    int s = csr_src[e];
    float2 v = __half22float2(*(const __half2*)(hs + (size_t)s * D + l * 2));
    acc0 += v.x;
    acc1 += v.y;
  }

  float o0 = wd * (acc0 + hv.x);
  float o1 = wd * (acc1 + hv.y);
  if (HASBIAS) { o0 += bv.x; o1 += bv.y; }
  if (RELU) { o0 = fmaxf(o0, 0.f); o1 = fmaxf(o1, 0.f); }
  if (POSTSCALE) { o0 *= wd; o1 *= wd; }
  if (OUTHALF) {
    *(__half2*)((__half*)out + (size_t)gw * D + l * 2) = __floats2half2_rn(o0, o1);
  } else {
    *(float2*)((float*)out + (size_t)gw * D + l * 2) = make_float2(o0, o1);
  }
}

#define DEF_AGG(NAME, D, RELU, HASBIAS, POSTSCALE, OUTHALF)                                \
  __global__ void NAME(const __half* __restrict__ hs, const int* __restrict__ row_ptr,     \
                       const int* __restrict__ csr_src, const float* __restrict__ isd,     \
                       const float* __restrict__ bias, void* __restrict__ out, int n) {    \
    agg_body<D, RELU, HASBIAS, POSTSCALE, OUTHALF>(hs, row_ptr, csr_src, isd, bias, out, n); \
  }
DEF_AGG(agg1_d128_biasrelu_f16, 128, true, true, false, true)
DEF_AGG(agg2_d64_bias_ps_f16, 64, false, true, true, true)
DEF_AGG(agg3_d64_plain_f16, 64, false, false, false, true)
DEF_AGG(agg4_d128_bias_f32, 128, false, true, false, false)

static inline size_t align_up(size_t x, size_t a) { return (x + a - 1) & ~(a - 1); }

extern "C" void kernel_launch(void* const* d_in, const int* in_sizes, int n_in,
                              void* d_out, int out_size, void* d_ws, size_t ws_size,
                              hipStream_t stream) {
  const float* X  = (const float*)d_in[0];
  const float* W1 = (const float*)d_in[1];
  const float* b1 = (const float*)d_in[2];
  const float* W2 = (const float*)d_in[3];
  const float* b2 = (const float*)d_in[4];
  const float* W3 = (const float*)d_in[5];
  const float* b3 = (const float*)d_in[6];
  const float* W4 = (const float*)d_in[7];
  const float* b4 = (const float*)d_in[8];
  const int*   ei = (const int*)d_in[9];

  const int N = in_sizes[0] / 128;
  const int E = in_sizes[9] / 2;
  const int* src = ei;
  const int* dst = ei + E;
  float* OUT = (float*)d_out;

  const int NB = (N + (1 << BSHIFT) - 1) >> BSHIFT;  // 196 for N=100k (<=256)
  const int NCH = (E + CHUNK - 1) / CHUNK;           // 782 chunks

  char* ws = (char*)d_ws;
  size_t off = 0;
  auto alloc = [&](size_t bytes) { void* p = ws + off; off = align_up(off + bytes, 256); return p; };
  int*    row_ptr     = (int*)alloc(((size_t)N + 1) * 4);
  float*  isd         = (float*)alloc((size_t)N * 4);
  int*    csr_src     = (int*)alloc((size_t)E * 4);
  int*    bucket_cur  = (int*)alloc(256 * 4);
  int*    bucket_base = (int*)alloc(256 * 4);
  __half* B1          = (__half*)alloc((size_t)N * 128 * 2);
  __half* B2          = (__half*)alloc((size_t)N * 128 * 2);
  __half* Fa = B1;
  __half* Fb = B1 + (size_t)N * 64;
  int2*   pairs = (int2*)B1;  // 19.3MB <= 25.6MB; dead before gemm1 writes B1

  hipMemsetAsync(bucket_cur, 0, 256 * 4, stream);

  binpass_kernel<<<NCH, 256, 0, stream>>>(src, dst, bucket_cur, pairs, E, NB);
  bedge_scan_kernel<<<1, 256, 0, stream>>>(bucket_cur, bucket_base, row_ptr, NB, N, E);
  bucket_work_kernel<<<NB, 256, 0, stream>>>(pairs, bucket_cur, bucket_base, isd, row_ptr, csr_src, N);

  const int gm = (N + 63) / 64;
  const int ab128 = (int)(((size_t)N * 64 + 255) / 256);
  const int ab64  = (int)(((size_t)N * 32 + 255) / 256);

  // L1: B1 = f16(isd*(X@W1)) ; B2 = z1 = f16(relu(P'+b1))
  gemm1_mfma_k128_n128<<<dim3(gm, 2), 256, 0, stream>>>(X, W1, isd, B1, N);
  agg1_d128_biasrelu_f16<<<ab128, 256, 0, stream>>>(B1, row_ptr, csr_src, isd, b1, B2, N);
  // L2: Fa = f16(isd*(z1@W2)) ; Fb = f16(isd*(P'+b2))
  gemm2_mfma_k128_n64<<<dim3(gm, 1), 256, 0, stream>>>(B2, W2, isd, Fa, N);
  agg2_d64_bias_ps_f16<<<ab64, 256, 0, stream>>>(Fa, row_ptr, csr_src, isd, b2, Fb, N);
  // L3: G(=Fa) = f16(P(z2)) ; B2 = z3 = f16(relu(G@W3+b3))
  agg3_d64_plain_f16<<<ab64, 256, 0, stream>>>(Fb, row_ptr, csr_src, isd, nullptr, Fa, N);
  gemm3_mfma_k64_n128<<<dim3(gm, 2), 256, 0, stream>>>(Fa, W3, b3, B2, N);
  // L4: B1 = f16(isd*(z3@W4)) ; out = P'+b4 -> OUT (fp32)
  gemm4_mfma_k128_n128<<<dim3(gm, 2), 256, 0, stream>>>(B2, W4, isd, B1, N);
  agg4_d128_bias_f32<<<ab128, 256, 0, stream>>>(B1, row_ptr, csr_src, isd, b4, OUT, N);
}

// Round 10
// 318.039 us; speedup vs baseline: 2.3433x; 1.0499x over previous
//
#include <hip/hip_runtime.h>
#include <hip/hip_fp16.h>

typedef _Float16 f16x8 __attribute__((ext_vector_type(8)));
typedef _Float16 f16x4 __attribute__((ext_vector_type(4)));
typedef float f32x4 __attribute__((ext_vector_type(4)));

#define CHUNK 4096
#define BSHIFT 9          // 512 dsts per bucket
#define CAP 12288         // bucket run capacity; E*512/N ~= 8192 expected

// ---------------------------------------------------------------------------
// 4-layer GCN, all intermediates fp16 (fp32 accumulate everywhere):
//   P(Y)_d = isd_d * (sum_{e:dst=d} Ys_src + Ys_d)  with Ys = isd*Y (pre-scaled)
// X and W pre-converted to fp16 once (Xh row-major, Wt transposed) so GEMMs
// stage pure f16x8 vector loads with zero per-block conversion (r9: ~90us).
// ---------------------------------------------------------------------------

// bin edges into fixed-capacity bucket runs; 1 global atomic per (block,bucket)
static __global__ void binpass_kernel(const int* __restrict__ src, const int* __restrict__ dst,
                                      int* __restrict__ bucket_cur, int2* __restrict__ pairs,
                                      int E, int NB) {
  __shared__ int lh[256], lbase[256], lcur[256];
  int t = threadIdx.x;
  lh[t] = 0;
  __syncthreads();
  int base = blockIdx.x * CHUNK;
  int end = min(base + CHUNK, E);
  for (int i = base + t; i < end; i += 256)
    atomicAdd(&lh[dst[i] >> BSHIFT], 1);
  __syncthreads();
  if (t < NB && lh[t]) lbase[t] = atomicAdd(&bucket_cur[t], lh[t]);
  lcur[t] = 0;
  __syncthreads();
  for (int i = base + t; i < end; i += 256) {
    int s = src[i], d = dst[i];
    int b = d >> BSHIFT;
    int p = lbase[b] + atomicAdd(&lcur[b], 1);
    if (p < CAP) pairs[(size_t)b * CAP + p] = make_int2(s, d);
  }
}

// exclusive scan of bucket counts -> global edge offsets; row_ptr[n] = E
static __global__ void bedge_scan_kernel(const int* __restrict__ bucket_cur,
                                         int* __restrict__ bucket_base,
                                         int* __restrict__ row_ptr, int NB, int n, int E) {
  __shared__ int sh[256];
  int t = threadIdx.x;
  int v = (t < NB) ? bucket_cur[t] : 0;
  sh[t] = v;
  __syncthreads();
  for (int off = 1; off < 256; off <<= 1) {
    int x = (t >= off) ? sh[t - off] : 0;
    __syncthreads();
    sh[t] += x;
    __syncthreads();
  }
  if (t < NB) bucket_base[t] = sh[t] - v;
  if (t == 0) row_ptr[n] = E;
}

// one block per bucket: LDS degree hist -> LDS scan -> coalesced row_ptr/isd
// writes -> LDS-cursor CSR fill within the bucket's contiguous span.
static __global__ void bucket_work_kernel(const int2* __restrict__ pairs,
                                          const int* __restrict__ bucket_cur,
                                          const int* __restrict__ bucket_base,
                                          float* __restrict__ isd, int* __restrict__ row_ptr,
                                          int* __restrict__ csr_src, int n) {
  __shared__ int lcnt[512];
  __shared__ int lcur[512];
  __shared__ int s2[256];
  int b = blockIdx.x;
  int t = threadIdx.x;
  int d0 = b << BSHIFT;
  int cnt = bucket_cur[b];
  int base = bucket_base[b];
  const int2* bp = pairs + (size_t)b * CAP;
  lcnt[t] = 0;
  lcnt[t + 256] = 0;
  __syncthreads();
  for (int i = t; i < cnt; i += 256)
    atomicAdd(&lcnt[bp[i].y - d0], 1);
  __syncthreads();
  int a0 = lcnt[2 * t], a1 = lcnt[2 * t + 1];
  s2[t] = a0 + a1;
  __syncthreads();
  for (int off = 1; off < 256; off <<= 1) {
    int x = (t >= off) ? s2[t - off] : 0;
    __syncthreads();
    s2[t] += x;
    __syncthreads();
  }
  int excl = s2[t] - (a0 + a1);
  int d = d0 + 2 * t;
  if (d < n)     { row_ptr[d]     = base + excl;      isd[d]     = rsqrtf((float)a0 + 1.0f); }
  if (d + 1 < n) { row_ptr[d + 1] = base + excl + a0; isd[d + 1] = rsqrtf((float)a1 + 1.0f); }
  lcur[2 * t] = excl;
  lcur[2 * t + 1] = excl + a0;
  __syncthreads();
  for (int i = t; i < cnt; i += 256) {
    int2 e = bp[i];
    int p = atomicAdd(&lcur[e.y - d0], 1);
    csr_src[base + p] = e.x;
  }
}

// ---------------------------------------------------------------------------
// Pre-conversion: X fp32 -> fp16 (vectorized), W_i -> transposed fp16.
// ---------------------------------------------------------------------------
static __global__ void cvt_x_kernel(const float* __restrict__ X, __half* __restrict__ Xh,
                                    int total8) {
  int i = blockIdx.x * blockDim.x + threadIdx.x;
  if (i >= total8) return;
  float4 a = *(const float4*)&X[(size_t)i * 8];
  float4 b = *(const float4*)&X[(size_t)i * 8 + 4];
  f16x8 v;
  v[0] = (_Float16)a.x; v[1] = (_Float16)a.y; v[2] = (_Float16)a.z; v[3] = (_Float16)a.w;
  v[4] = (_Float16)b.x; v[5] = (_Float16)b.y; v[6] = (_Float16)b.z; v[7] = (_Float16)b.w;
  *(f16x8*)&Xh[(size_t)i * 8] = v;
}

// transpose-convert all 4 weight matrices: Wt[c][k] = (half)W[k][c]
static __global__ void wt_all_kernel(const float* __restrict__ W1, const float* __restrict__ W2,
                                     const float* __restrict__ W3, const float* __restrict__ W4,
                                     __half* __restrict__ T1, __half* __restrict__ T2,
                                     __half* __restrict__ T3, __half* __restrict__ T4) {
  int m = blockIdx.y;
  const float* W; __half* T; int K, NO, sh;
  if (m == 0)      { W = W1; T = T1; K = 128; NO = 128; sh = 7; }
  else if (m == 1) { W = W2; T = T2; K = 128; NO = 64;  sh = 6; }
  else if (m == 2) { W = W3; T = T3; K = 64;  NO = 128; sh = 7; }
  else             { W = W4; T = T4; K = 128; NO = 128; sh = 7; }
  int total = K * NO;
  for (int idx = blockIdx.x * 256 + threadIdx.x; idx < total; idx += gridDim.x * 256) {
    int k = idx >> sh, c = idx & (NO - 1);
    T[(size_t)c * K + k] = __float2half(W[idx]);
  }
}

// ---------------------------------------------------------------------------
// MFMA GEMM v2: H[n,NOUT](f16) = epi(Xh[n,K] @ Wt^T) ; fp32 accumulate.
// BM=64 x BN=NOUT full-width tile, 4 waves (2M x 2N), wave = 32 x NOUT/2.
// All staging is f16x8 vector loads (Xh row-major, Wt[c][k] transposed).
// EPI 0: H = f16(isd[row]*acc)    EPI 1: H = f16(relu(acc + bias[col]))
// ---------------------------------------------------------------------------
template<int K, int NOUT, int EPI>
__device__ __forceinline__ void gemm_mfma_body(const __half* __restrict__ Xh,
                                               const __half* __restrict__ Wt,
                                               const float* __restrict__ aux,
                                               __half* __restrict__ H, int n) {
  __shared__ _Float16 ah[64][K + 8];
  __shared__ _Float16 bh[NOUT][K + 8];
  const int tid = threadIdx.x;
  const int bm = blockIdx.x * 64;

  for (int i = tid; i < 64 * (K / 8); i += 256) {
    int r = i / (K / 8), c8 = i % (K / 8);
    int gr = bm + r;
    f16x8 v = {};
    if (gr < n) v = *(const f16x8*)&Xh[(size_t)gr * K + c8 * 8];
    *(f16x8*)&ah[r][c8 * 8] = v;
  }
  for (int i = tid; i < NOUT * (K / 8); i += 256) {
    int c = i / (K / 8), k8 = i % (K / 8);
    *(f16x8*)&bh[c][k8 * 8] = *(const f16x8*)&Wt[(size_t)c * K + k8 * 8];
  }
  __syncthreads();

  const int lane = tid & 63;
  const int wid = tid >> 6;
  constexpr int WN = NOUT / 2;   // wave N-extent
  constexpr int NF = WN / 16;    // N frags per wave (4 or 2)
  const int wm = (wid >> 1) * 32;
  const int wn = (wid & 1) * WN;
  const int lr = lane & 15;
  const int lk = (lane >> 4) * 8;

  f32x4 acc[2][NF] = {};
#pragma unroll
  for (int ks = 0; ks < K; ks += 32) {
    f16x8 a0 = *(const f16x8*)&ah[wm + lr][ks + lk];
    f16x8 a1 = *(const f16x8*)&ah[wm + 16 + lr][ks + lk];
#pragma unroll
    for (int tn = 0; tn < NF; ++tn) {
      f16x8 b = *(const f16x8*)&bh[wn + tn * 16 + lr][ks + lk];
      acc[0][tn] = __builtin_amdgcn_mfma_f32_16x16x32_f16(a0, b, acc[0][tn], 0, 0, 0);
      acc[1][tn] = __builtin_amdgcn_mfma_f32_16x16x32_f16(a1, b, acc[1][tn], 0, 0, 0);
    }
  }

  float bcol[NF];
#pragma unroll
  for (int tn = 0; tn < NF; ++tn)
    bcol[tn] = (EPI == 1) ? aux[wn + tn * 16 + lr] : 0.f;
  const int rgrp = (lane >> 4) * 4;
#pragma unroll
  for (int tm = 0; tm < 2; ++tm) {
    int rb = bm + wm + tm * 16 + rgrp;
#pragma unroll
    for (int r = 0; r < 4; ++r) {
      int row = rb + r;
      if (row >= n) continue;
      float s = (EPI == 0) ? aux[row] : 0.f;
#pragma unroll
      for (int tn = 0; tn < NF; ++tn) {
        float v = acc[tm][tn][r];
        if (EPI == 0) v *= s;
        else v = fmaxf(v + bcol[tn], 0.f);
        H[(size_t)row * NOUT + wn + tn * 16 + lr] = __float2half(v);
      }
    }
  }
}

#define DEF_GEMM(NAME, K, NOUT, EPI)                                                     \
  __global__ __launch_bounds__(256, 2) void NAME(const __half* __restrict__ Xh,          \
                                                 const __half* __restrict__ Wt,          \
                                                 const float* __restrict__ aux,          \
                                                 __half* __restrict__ H, int n) {        \
    gemm_mfma_body<K, NOUT, EPI>(Xh, Wt, aux, H, n);                                     \
  }
DEF_GEMM(gemm1_mfma_k128_n128, 128, 128, 0)
DEF_GEMM(gemm2_mfma_k128_n64, 128, 64, 0)
DEF_GEMM(gemm3_mfma_k64_n128, 64, 128, 1)
DEF_GEMM(gemm4_mfma_k128_n128, 128, 128, 0)

// ---------------------------------------------------------------------------
// Aggregation over fp16 pre-scaled rows (fp32 accumulate), f16x4 (8B/lane):
// D=128: 32 lanes/node, 2 nodes/wave.  D=64: 16 lanes/node, 4 nodes/wave.
// Same bytes as r9, half the load instructions (transaction-rate probe).
// ---------------------------------------------------------------------------
template<int D, bool RELU, bool HASBIAS, bool POSTSCALE, bool OUTHALF>
__device__ __forceinline__ void agg_body(const __half* __restrict__ hs, const int* __restrict__ row_ptr,
                                         const int* __restrict__ csr_src, const float* __restrict__ isd,
                                         const float* __restrict__ bias, void* __restrict__ out, int n) {
  constexpr int LPN = D / 4;     // lanes per node
  int w = (blockIdx.x * blockDim.x + threadIdx.x) >> 6;
  int lane = threadIdx.x & 63;
  int li = lane & (LPN - 1);
  int gw = w * (64 / LPN) + (lane / LPN);
  if (gw >= n) return;

  float wd = isd[gw];
  f16x4 hv = *(const f16x4*)(hs + (size_t)gw * D + li * 4);
  float4 bv = make_float4(0.f, 0.f, 0.f, 0.f);
  if (HASBIAS) bv = *(const float4*)(bias + li * 4);

  int beg = row_ptr[gw], end = row_ptr[gw + 1];
  float a0 = 0.f, a1 = 0.f, a2 = 0.f, a3 = 0.f;

  int e = beg;
  int s0 = 0, s1 = 0, s2 = 0, s3 = 0;
  if (e + 4 <= end) {
    s0 = csr_src[e + 0]; s1 = csr_src[e + 1];
    s2 = csr_src[e + 2]; s3 = csr_src[e + 3];
  }
  while (e + 4 <= end) {
    f16x4 v0 = *(const f16x4*)(hs + (size_t)s0 * D + li * 4);
    f16x4 v1 = *(const f16x4*)(hs + (size_t)s1 * D + li * 4);
    f16x4 v2 = *(const f16x4*)(hs + (size_t)s2 * D + li * 4);
    f16x4 v3 = *(const f16x4*)(hs + (size_t)s3 * D + li * 4);
    int en = e + 4;
    if (en + 4 <= end) {
      s0 = csr_src[en + 0]; s1 = csr_src[en + 1];
      s2 = csr_src[en + 2]; s3 = csr_src[en + 3];
    }
    a0 += ((float)v0[0] + (float)v1[0]) + ((float)v2[0] + (float)v3[0]);
    a1 += ((float)v0[1] + (float)v1[1]) + ((float)v2[1] + (float)v3[1]);
    a2 += ((float)v0[2] + (float)v1[2]) + ((float)v2[2] + (float)v3[2]);
    a3 += ((float)v0[3] + (float)v1[3]) + ((float)v2[3] + (float)v3[3]);
    e = en;
  }
  for (; e < end; ++e) {
    int s = csr_src[e];
    f16x4 v = *(const f16x4*)(hs + (size_t)s * D + li * 4);
    a0 += (float)v[0]; a1 += (float)v[1]; a2 += (float)v[2]; a3 += (float)v[3];
  }

  float o0 = wd * (a0 + (float)hv[0]);
  float o1 = wd * (a1 + (float)hv[1]);
  float o2 = wd * (a2 + (float)hv[2]);
  float o3 = wd * (a3 + (float)hv[3]);
  if (HASBIAS) { o0 += bv.x; o1 += bv.y; o2 += bv.z; o3 += bv.w; }
  if (RELU) {
    o0 = fmaxf(o0, 0.f); o1 = fmaxf(o1, 0.f);
    o2 = fmaxf(o2, 0.f); o3 = fmaxf(o3, 0.f);
  }
  if (POSTSCALE) { o0 *= wd; o1 *= wd; o2 *= wd; o3 *= wd; }
  if (OUTHALF) {
    f16x4 ov;
    ov[0] = (_Float16)o0; ov[1] = (_Float16)o1; ov[2] = (_Float16)o2; ov[3] = (_Float16)o3;
    *(f16x4*)((__half*)out + (size_t)gw * D + li * 4) = ov;
  } else {
    *(float4*)((float*)out + (size_t)gw * D + li * 4) = make_float4(o0, o1, o2, o3);
  }
}

#define DEF_AGG(NAME, D, RELU, HASBIAS, POSTSCALE, OUTHALF)                                \
  __global__ void NAME(const __half* __restrict__ hs, const int* __restrict__ row_ptr,     \
                       const int* __restrict__ csr_src, const float* __restrict__ isd,     \
                       const float* __restrict__ bias, void* __restrict__ out, int n) {    \
    agg_body<D, RELU, HASBIAS, POSTSCALE, OUTHALF>(hs, row_ptr, csr_src, isd, bias, out, n); \
  }
DEF_AGG(agg1_d128_biasrelu_f16, 128, true, true, false, true)
DEF_AGG(agg2_d64_bias_ps_f16, 64, false, true, true, true)
DEF_AGG(agg3_d64_plain_f16, 64, false, false, false, true)
DEF_AGG(agg4_d128_bias_f32, 128, false, true, false, false)

static inline size_t align_up(size_t x, size_t a) { return (x + a - 1) & ~(a - 1); }

extern "C" void kernel_launch(void* const* d_in, const int* in_sizes, int n_in,
                              void* d_out, int out_size, void* d_ws, size_t ws_size,
                              hipStream_t stream) {
  const float* X  = (const float*)d_in[0];
  const float* W1 = (const float*)d_in[1];
  const float* b1 = (const float*)d_in[2];
  const float* W2 = (const float*)d_in[3];
  const float* b2 = (const float*)d_in[4];
  const float* W3 = (const float*)d_in[5];
  const float* b3 = (const float*)d_in[6];
  const float* W4 = (const float*)d_in[7];
  const float* b4 = (const float*)d_in[8];
  const int*   ei = (const int*)d_in[9];

  const int N = in_sizes[0] / 128;
  const int E = in_sizes[9] / 2;
  const int* src = ei;
  const int* dst = ei + E;
  float* OUT = (float*)d_out;

  const int NB = (N + (1 << BSHIFT) - 1) >> BSHIFT;  // 196 for N=100k (<=256)
  const int NCH = (E + CHUNK - 1) / CHUNK;           // 391 chunks

  char* ws = (char*)d_ws;
  size_t off = 0;
  auto alloc = [&](size_t bytes) { void* p = ws + off; off = align_up(off + bytes, 256); return p; };
  int*    row_ptr     = (int*)alloc(((size_t)N + 1) * 4);
  float*  isd         = (float*)alloc((size_t)N * 4);
  int*    csr_src     = (int*)alloc((size_t)E * 4);
  int*    bucket_cur  = (int*)alloc(256 * 4);
  int*    bucket_base = (int*)alloc(256 * 4);
  __half* Wt1         = (__half*)alloc(128 * 128 * 2);
  __half* Wt2         = (__half*)alloc(128 * 64 * 2);
  __half* Wt3         = (__half*)alloc(64 * 128 * 2);
  __half* Wt4         = (__half*)alloc(128 * 128 * 2);
  __half* Xh          = (__half*)alloc((size_t)N * 128 * 2);  // also B2 (z1/z3) later
  __half* B1          = (__half*)alloc((size_t)N * 128 * 2);  // also pairs earlier
  __half* B2 = Xh;                   // alias: Xh dead after gemm1
  __half* Fa = B1;                   // N x 64 f16 view
  __half* Fb = B1 + (size_t)N * 64;  // N x 64 f16 view
  int2*   pairs = (int2*)B1;         // 19.3MB <= 25.6MB; dead before gemm1 writes B1

  hipMemsetAsync(bucket_cur, 0, 256 * 4, stream);

  // CSR build
  binpass_kernel<<<NCH, 256, 0, stream>>>(src, dst, bucket_cur, pairs, E, NB);
  bedge_scan_kernel<<<1, 256, 0, stream>>>(bucket_cur, bucket_base, row_ptr, NB, N, E);
  bucket_work_kernel<<<NB, 256, 0, stream>>>(pairs, bucket_cur, bucket_base, isd, row_ptr, csr_src, N);

  // pre-convert inputs
  int total8 = N * 128 / 8;
  cvt_x_kernel<<<(total8 + 255) / 256, 256, 0, stream>>>(X, Xh, total8);
  wt_all_kernel<<<dim3(16, 4), 256, 0, stream>>>(W1, W2, W3, W4, Wt1, Wt2, Wt3, Wt4);

  const int gm = (N + 63) / 64;
  const int ab128 = (N + 7) / 8;    // 2 nodes/wave, 8 nodes/block
  const int ab64  = (N + 15) / 16;  // 4 nodes/wave, 16 nodes/block

  // L1: B1 = f16(isd*(Xh@W1)) ; B2 = z1 = f16(relu(P'+b1))
  gemm1_mfma_k128_n128<<<gm, 256, 0, stream>>>(Xh, Wt1, isd, B1, N);
  agg1_d128_biasrelu_f16<<<ab128, 256, 0, stream>>>(B1, row_ptr, csr_src, isd, b1, B2, N);
  // L2: Fa = f16(isd*(z1@W2)) ; Fb = f16(isd*(P'+b2))
  gemm2_mfma_k128_n64<<<gm, 256, 0, stream>>>(B2, Wt2, isd, Fa, N);
  agg2_d64_bias_ps_f16<<<ab64, 256, 0, stream>>>(Fa, row_ptr, csr_src, isd, b2, Fb, N);
  // L3: G(=Fa) = f16(P(z2)) ; B2 = z3 = f16(relu(G@W3+b3))
  agg3_d64_plain_f16<<<ab64, 256, 0, stream>>>(Fb, row_ptr, csr_src, isd, nullptr, Fa, N);
  gemm3_mfma_k64_n128<<<gm, 256, 0, stream>>>(Fa, Wt3, b3, B2, N);
  // L4: B1 = f16(isd*(z3@W4)) ; out = P'+b4 -> OUT (fp32)
  gemm4_mfma_k128_n128<<<gm, 256, 0, stream>>>(B2, Wt4, isd, B1, N);
  agg4_d128_bias_f32<<<ab128, 256, 0, stream>>>(B1, row_ptr, csr_src, isd, b4, OUT, N);
}

// Round 11
// 310.760 us; speedup vs baseline: 2.3982x; 1.0234x over previous
//
#include <hip/hip_runtime.h>
#include <hip/hip_fp16.h>

typedef _Float16 f16x8 __attribute__((ext_vector_type(8)));
typedef _Float16 f16x4 __attribute__((ext_vector_type(4)));
typedef float f32x4 __attribute__((ext_vector_type(4)));

#define CHUNK 4096
#define BSHIFT 9          // 512 dsts per bucket
#define CAP 12288         // bucket run capacity; E*512/N ~= 8192 expected

// ---------------------------------------------------------------------------
// 4-layer GCN, all intermediates fp16 (fp32 accumulate everywhere):
//   P(Y)_d = isd_d * (sum_{e:dst=d} Ys_src + Ys_d)  with Ys = isd*Y (pre-scaled)
// Aggs sit at the measured random-gather ceiling (~3.9 TB/s L2-miss traffic,
// FETCH = 8-XCD replication floor) -- r5/r9/r10 rate-invariance evidence.
// This round: cvt_x fused into gemm1 staging; pairs packed to uint32.
// ---------------------------------------------------------------------------

// bin edges into fixed-capacity bucket runs; 1 global atomic per (block,bucket)
// pairs packed: (dst_local<<23) | src   (src < 2^23, dst_local < 2^9)
static __global__ void binpass_kernel(const int* __restrict__ src, const int* __restrict__ dst,
                                      int* __restrict__ bucket_cur, unsigned* __restrict__ pairs,
                                      int E, int NB) {
  __shared__ int lh[256], lbase[256], lcur[256];
  int t = threadIdx.x;
  lh[t] = 0;
  __syncthreads();
  int base = blockIdx.x * CHUNK;
  int end = min(base + CHUNK, E);
  for (int i = base + t; i < end; i += 256)
    atomicAdd(&lh[dst[i] >> BSHIFT], 1);
  __syncthreads();
  if (t < NB && lh[t]) lbase[t] = atomicAdd(&bucket_cur[t], lh[t]);
  lcur[t] = 0;
  __syncthreads();
  for (int i = base + t; i < end; i += 256) {
    int s = src[i], d = dst[i];
    int b = d >> BSHIFT;
    int p = lbase[b] + atomicAdd(&lcur[b], 1);
    unsigned pk = ((unsigned)(d & ((1 << BSHIFT) - 1)) << 23) | (unsigned)s;
    if (p < CAP) pairs[(size_t)b * CAP + p] = pk;
  }
}

// exclusive scan of bucket counts -> global edge offsets; row_ptr[n] = E
static __global__ void bedge_scan_kernel(const int* __restrict__ bucket_cur,
                                         int* __restrict__ bucket_base,
                                         int* __restrict__ row_ptr, int NB, int n, int E) {
  __shared__ int sh[256];
  int t = threadIdx.x;
  int v = (t < NB) ? bucket_cur[t] : 0;
  sh[t] = v;
  __syncthreads();
  for (int off = 1; off < 256; off <<= 1) {
    int x = (t >= off) ? sh[t - off] : 0;
    __syncthreads();
    sh[t] += x;
    __syncthreads();
  }
  if (t < NB) bucket_base[t] = sh[t] - v;
  if (t == 0) row_ptr[n] = E;
}

// one block per bucket: LDS degree hist -> LDS scan -> coalesced row_ptr/isd
// writes -> LDS-cursor CSR fill within the bucket's contiguous span.
static __global__ void bucket_work_kernel(const unsigned* __restrict__ pairs,
                                          const int* __restrict__ bucket_cur,
                                          const int* __restrict__ bucket_base,
                                          float* __restrict__ isd, int* __restrict__ row_ptr,
                                          int* __restrict__ csr_src, int n) {
  __shared__ int lcnt[512];
  __shared__ int lcur[512];
  __shared__ int s2[256];
  int b = blockIdx.x;
  int t = threadIdx.x;
  int d0 = b << BSHIFT;
  int cnt = bucket_cur[b];
  int base = bucket_base[b];
  const unsigned* bp = pairs + (size_t)b * CAP;
  lcnt[t] = 0;
  lcnt[t + 256] = 0;
  __syncthreads();
  for (int i = t; i < cnt; i += 256)
    atomicAdd(&lcnt[bp[i] >> 23], 1);
  __syncthreads();
  int a0 = lcnt[2 * t], a1 = lcnt[2 * t + 1];
  s2[t] = a0 + a1;
  __syncthreads();
  for (int off = 1; off < 256; off <<= 1) {
    int x = (t >= off) ? s2[t - off] : 0;
    __syncthreads();
    s2[t] += x;
    __syncthreads();
  }
  int excl = s2[t] - (a0 + a1);
  int d = d0 + 2 * t;
  if (d < n)     { row_ptr[d]     = base + excl;      isd[d]     = rsqrtf((float)a0 + 1.0f); }
  if (d + 1 < n) { row_ptr[d + 1] = base + excl + a0; isd[d + 1] = rsqrtf((float)a1 + 1.0f); }
  lcur[2 * t] = excl;
  lcur[2 * t + 1] = excl + a0;
  __syncthreads();
  for (int i = t; i < cnt; i += 256) {
    unsigned e = bp[i];
    int p = atomicAdd(&lcur[e >> 23], 1);
    csr_src[base + p] = (int)(e & 0x7FFFFFu);
  }
}

// transpose-convert all 4 weight matrices: Wt[c][k] = (half)W[k][c]
static __global__ void wt_all_kernel(const float* __restrict__ W1, const float* __restrict__ W2,
                                     const float* __restrict__ W3, const float* __restrict__ W4,
                                     __half* __restrict__ T1, __half* __restrict__ T2,
                                     __half* __restrict__ T3, __half* __restrict__ T4) {
  int m = blockIdx.y;
  const float* W; __half* T; int K, NO, sh;
  if (m == 0)      { W = W1; T = T1; K = 128; NO = 128; sh = 7; }
  else if (m == 1) { W = W2; T = T2; K = 128; NO = 64;  sh = 6; }
  else if (m == 2) { W = W3; T = T3; K = 64;  NO = 128; sh = 7; }
  else             { W = W4; T = T4; K = 128; NO = 128; sh = 7; }
  int total = K * NO;
  for (int idx = blockIdx.x * 256 + threadIdx.x; idx < total; idx += gridDim.x * 256) {
    int k = idx >> sh, c = idx & (NO - 1);
    T[(size_t)c * K + k] = __float2half(W[idx]);
  }
}

// ---------------------------------------------------------------------------
// MFMA GEMM: H[n,NOUT](f16) = epi(X[n,K] @ Wt^T) ; fp32 accumulate.
// BM=64 x BN=NOUT full-width tile, 4 waves (2M x 2N), wave = 32 x NOUT/2.
// AHALF=0: stage-converts fp32 X (fuses the old cvt_x pass into gemm1).
// EPI 0: H = f16(isd[row]*acc)    EPI 1: H = f16(relu(acc + bias[col]))
// ---------------------------------------------------------------------------
template<int K, int NOUT, bool AHALF, int EPI>
__device__ __forceinline__ void gemm_mfma_body(const void* __restrict__ Xin,
                                               const __half* __restrict__ Wt,
                                               const float* __restrict__ aux,
                                               __half* __restrict__ H, int n) {
  __shared__ _Float16 ah[64][K + 8];
  __shared__ _Float16 bh[NOUT][K + 8];
  const int tid = threadIdx.x;
  const int bm = blockIdx.x * 64;

  if (AHALF) {
    const __half* Xh = (const __half*)Xin;
    for (int i = tid; i < 64 * (K / 8); i += 256) {
      int r = i / (K / 8), c8 = i % (K / 8);
      int gr = bm + r;
      f16x8 v = {};
      if (gr < n) v = *(const f16x8*)&Xh[(size_t)gr * K + c8 * 8];
      *(f16x8*)&ah[r][c8 * 8] = v;
    }
  } else {
    const float* Xf = (const float*)Xin;
    for (int i = tid; i < 64 * (K / 8); i += 256) {
      int r = i / (K / 8), c8 = i % (K / 8);
      int gr = bm + r;
      f16x8 v = {};
      if (gr < n) {
        float4 a = *(const float4*)&Xf[(size_t)gr * K + c8 * 8];
        float4 b = *(const float4*)&Xf[(size_t)gr * K + c8 * 8 + 4];
        v[0] = (_Float16)a.x; v[1] = (_Float16)a.y; v[2] = (_Float16)a.z; v[3] = (_Float16)a.w;
        v[4] = (_Float16)b.x; v[5] = (_Float16)b.y; v[6] = (_Float16)b.z; v[7] = (_Float16)b.w;
      }
      *(f16x8*)&ah[r][c8 * 8] = v;
    }
  }
  for (int i = tid; i < NOUT * (K / 8); i += 256) {
    int c = i / (K / 8), k8 = i % (K / 8);
    *(f16x8*)&bh[c][k8 * 8] = *(const f16x8*)&Wt[(size_t)c * K + k8 * 8];
  }
  __syncthreads();

  const int lane = tid & 63;
  const int wid = tid >> 6;
  constexpr int WN = NOUT / 2;   // wave N-extent
  constexpr int NF = WN / 16;    // N frags per wave (4 or 2)
  const int wm = (wid >> 1) * 32;
  const int wn = (wid & 1) * WN;
  const int lr = lane & 15;
  const int lk = (lane >> 4) * 8;

  f32x4 acc[2][NF] = {};
#pragma unroll
  for (int ks = 0; ks < K; ks += 32) {
    f16x8 a0 = *(const f16x8*)&ah[wm + lr][ks + lk];
    f16x8 a1 = *(const f16x8*)&ah[wm + 16 + lr][ks + lk];
#pragma unroll
    for (int tn = 0; tn < NF; ++tn) {
      f16x8 b = *(const f16x8*)&bh[wn + tn * 16 + lr][ks + lk];
      acc[0][tn] = __builtin_amdgcn_mfma_f32_16x16x32_f16(a0, b, acc[0][tn], 0, 0, 0);
      acc[1][tn] = __builtin_amdgcn_mfma_f32_16x16x32_f16(a1, b, acc[1][tn], 0, 0, 0);
    }
  }

  float bcol[NF];
#pragma unroll
  for (int tn = 0; tn < NF; ++tn)
    bcol[tn] = (EPI == 1) ? aux[wn + tn * 16 + lr] : 0.f;
  const int rgrp = (lane >> 4) * 4;
#pragma unroll
  for (int tm = 0; tm < 2; ++tm) {
    int rb = bm + wm + tm * 16 + rgrp;
#pragma unroll
    for (int r = 0; r < 4; ++r) {
      int row = rb + r;
      if (row >= n) continue;
      float s = (EPI == 0) ? aux[row] : 0.f;
#pragma unroll
      for (int tn = 0; tn < NF; ++tn) {
        float v = acc[tm][tn][r];
        if (EPI == 0) v *= s;
        else v = fmaxf(v + bcol[tn], 0.f);
        H[(size_t)row * NOUT + wn + tn * 16 + lr] = __float2half(v);
      }
    }
  }
}

#define DEF_GEMM(NAME, K, NOUT, AHALF, EPI)                                              \
  __global__ __launch_bounds__(256, 2) void NAME(const void* __restrict__ Xin,           \
                                                 const __half* __restrict__ Wt,          \
                                                 const float* __restrict__ aux,          \
                                                 __half* __restrict__ H, int n) {        \
    gemm_mfma_body<K, NOUT, AHALF, EPI>(Xin, Wt, aux, H, n);                             \
  }
DEF_GEMM(gemm1_mfma_k128_n128, 128, 128, false, 0)
DEF_GEMM(gemm2_mfma_k128_n64, 128, 64, true, 0)
DEF_GEMM(gemm3_mfma_k64_n128, 64, 128, true, 1)
DEF_GEMM(gemm4_mfma_k128_n128, 128, 128, true, 0)

// ---------------------------------------------------------------------------
// Aggregation over fp16 pre-scaled rows (fp32 accumulate), f16x4 (8B/lane):
// D=128: 32 lanes/node, 2 nodes/wave.  D=64: 16 lanes/node, 4 nodes/wave.
// At the measured random-gather ceiling (~3.9 TB/s, FETCH = replication floor).
// ---------------------------------------------------------------------------
template<int D, bool RELU, bool HASBIAS, bool POSTSCALE, bool OUTHALF>
__device__ __forceinline__ void agg_body(const __half* __restrict__ hs, const int* __restrict__ row_ptr,
                                         const int* __restrict__ csr_src, const float* __restrict__ isd,
                                         const float* __restrict__ bias, void* __restrict__ out, int n) {
  constexpr int LPN = D / 4;     // lanes per node
  int w = (blockIdx.x * blockDim.x + threadIdx.x) >> 6;
  int lane = threadIdx.x & 63;
  int li = lane & (LPN - 1);
  int gw = w * (64 / LPN) + (lane / LPN);
  if (gw >= n) return;

  float wd = isd[gw];
  f16x4 hv = *(const f16x4*)(hs + (size_t)gw * D + li * 4);
  float4 bv = make_float4(0.f, 0.f, 0.f, 0.f);
  if (HASBIAS) bv = *(const float4*)(bias + li * 4);

  int beg = row_ptr[gw], end = row_ptr[gw + 1];
  float a0 = 0.f, a1 = 0.f, a2 = 0.f, a3 = 0.f;

  int e = beg;
  int s0 = 0, s1 = 0, s2 = 0, s3 = 0;
  if (e + 4 <= end) {
    s0 = csr_src[e + 0]; s1 = csr_src[e + 1];
    s2 = csr_src[e + 2]; s3 = csr_src[e + 3];
  }
  while (e + 4 <= end) {
    f16x4 v0 = *(const f16x4*)(hs + (size_t)s0 * D + li * 4);
    f16x4 v1 = *(const f16x4*)(hs + (size_t)s1 * D + li * 4);
    f16x4 v2 = *(const f16x4*)(hs + (size_t)s2 * D + li * 4);
    f16x4 v3 = *(const f16x4*)(hs + (size_t)s3 * D + li * 4);
    int en = e + 4;
    if (en + 4 <= end) {
      s0 = csr_src[en + 0]; s1 = csr_src[en + 1];
      s2 = csr_src[en + 2]; s3 = csr_src[en + 3];
    }
    a0 += ((float)v0[0] + (float)v1[0]) + ((float)v2[0] + (float)v3[0]);
    a1 += ((float)v0[1] + (float)v1[1]) + ((float)v2[1] + (float)v3[1]);
    a2 += ((float)v0[2] + (float)v1[2]) + ((float)v2[2] + (float)v3[2]);
    a3 += ((float)v0[3] + (float)v1[3]) + ((float)v2[3] + (float)v3[3]);
    e = en;
  }
  for (; e < end; ++e) {
    int s = csr_src[e];
    f16x4 v = *(const f16x4*)(hs + (size_t)s * D + li * 4);
    a0 += (float)v[0]; a1 += (float)v[1]; a2 += (float)v[2]; a3 += (float)v[3];
  }

  float o0 = wd * (a0 + (float)hv[0]);
  float o1 = wd * (a1 + (float)hv[1]);
  float o2 = wd * (a2 + (float)hv[2]);
  float o3 = wd * (a3 + (float)hv[3]);
  if (HASBIAS) { o0 += bv.x; o1 += bv.y; o2 += bv.z; o3 += bv.w; }
  if (RELU) {
    o0 = fmaxf(o0, 0.f); o1 = fmaxf(o1, 0.f);
    o2 = fmaxf(o2, 0.f); o3 = fmaxf(o3, 0.f);
  }
  if (POSTSCALE) { o0 *= wd; o1 *= wd; o2 *= wd; o3 *= wd; }
  if (OUTHALF) {
    f16x4 ov;
    ov[0] = (_Float16)o0; ov[1] = (_Float16)o1; ov[2] = (_Float16)o2; ov[3] = (_Float16)o3;
    *(f16x4*)((__half*)out + (size_t)gw * D + li * 4) = ov;
  } else {
    *(float4*)((float*)out + (size_t)gw * D + li * 4) = make_float4(o0, o1, o2, o3);
  }
}

#define DEF_AGG(NAME, D, RELU, HASBIAS, POSTSCALE, OUTHALF)                                \
  __global__ void NAME(const __half* __restrict__ hs, const int* __restrict__ row_ptr,     \
                       const int* __restrict__ csr_src, const float* __restrict__ isd,     \
                       const float* __restrict__ bias, void* __restrict__ out, int n) {    \
    agg_body<D, RELU, HASBIAS, POSTSCALE, OUTHALF>(hs, row_ptr, csr_src, isd, bias, out, n); \
  }
DEF_AGG(agg1_d128_biasrelu_f16, 128, true, true, false, true)
DEF_AGG(agg2_d64_bias_ps_f16, 64, false, true, true, true)
DEF_AGG(agg3_d64_plain_f16, 64, false, false, false, true)
DEF_AGG(agg4_d128_bias_f32, 128, false, true, false, false)

static inline size_t align_up(size_t x, size_t a) { return (x + a - 1) & ~(a - 1); }

extern "C" void kernel_launch(void* const* d_in, const int* in_sizes, int n_in,
                              void* d_out, int out_size, void* d_ws, size_t ws_size,
                              hipStream_t stream) {
  const float* X  = (const float*)d_in[0];
  const float* W1 = (const float*)d_in[1];
  const float* b1 = (const float*)d_in[2];
  const float* W2 = (const float*)d_in[3];
  const float* b2 = (const float*)d_in[4];
  const float* W3 = (const float*)d_in[5];
  const float* b3 = (const float*)d_in[6];
  const float* W4 = (const float*)d_in[7];
  const float* b4 = (const float*)d_in[8];
  const int*   ei = (const int*)d_in[9];

  const int N = in_sizes[0] / 128;
  const int E = in_sizes[9] / 2;
  const int* src = ei;
  const int* dst = ei + E;
  float* OUT = (float*)d_out;

  const int NB = (N + (1 << BSHIFT) - 1) >> BSHIFT;  // 196 for N=100k (<=256)
  const int NCH = (E + CHUNK - 1) / CHUNK;           // 391 chunks

  char* ws = (char*)d_ws;
  size_t off = 0;
  auto alloc = [&](size_t bytes) { void* p = ws + off; off = align_up(off + bytes, 256); return p; };
  int*    row_ptr     = (int*)alloc(((size_t)N + 1) * 4);
  float*  isd         = (float*)alloc((size_t)N * 4);
  int*    csr_src     = (int*)alloc((size_t)E * 4);
  int*    bucket_cur  = (int*)alloc(256 * 4);
  int*    bucket_base = (int*)alloc(256 * 4);
  __half* Wt1         = (__half*)alloc(128 * 128 * 2);
  __half* Wt2         = (__half*)alloc(128 * 64 * 2);
  __half* Wt3         = (__half*)alloc(64 * 128 * 2);
  __half* Wt4         = (__half*)alloc(128 * 128 * 2);
  __half* B1          = (__half*)alloc((size_t)N * 128 * 2);
  __half* B2          = (__half*)alloc((size_t)N * 128 * 2);
  __half* Fa = B1;                   // N x 64 f16 view
  __half* Fb = B1 + (size_t)N * 64;  // N x 64 f16 view
  unsigned* pairs = (unsigned*)B1;   // 9.7MB (196*12288*4) <= 25.6MB; dead before gemm1

  hipMemsetAsync(bucket_cur, 0, 256 * 4, stream);

  // CSR build
  binpass_kernel<<<NCH, 256, 0, stream>>>(src, dst, bucket_cur, pairs, E, NB);
  bedge_scan_kernel<<<1, 256, 0, stream>>>(bucket_cur, bucket_base, row_ptr, NB, N, E);
  bucket_work_kernel<<<NB, 256, 0, stream>>>(pairs, bucket_cur, bucket_base, isd, row_ptr, csr_src, N);

  // weight transpose-convert (X conversion fused into gemm1 staging)
  wt_all_kernel<<<dim3(16, 4), 256, 0, stream>>>(W1, W2, W3, W4, Wt1, Wt2, Wt3, Wt4);

  const int gm = (N + 63) / 64;
  const int ab128 = (N + 7) / 8;    // 2 nodes/wave, 8 nodes/block
  const int ab64  = (N + 15) / 16;  // 4 nodes/wave, 16 nodes/block

  // L1: B1 = f16(isd*(X@W1)) ; B2 = z1 = f16(relu(P'+b1))
  gemm1_mfma_k128_n128<<<gm, 256, 0, stream>>>(X, Wt1, isd, B1, N);
  agg1_d128_biasrelu_f16<<<ab128, 256, 0, stream>>>(B1, row_ptr, csr_src, isd, b1, B2, N);
  // L2: Fa = f16(isd*(z1@W2)) ; Fb = f16(isd*(P'+b2))
  gemm2_mfma_k128_n64<<<gm, 256, 0, stream>>>(B2, Wt2, isd, Fa, N);
  agg2_d64_bias_ps_f16<<<ab64, 256, 0, stream>>>(Fa, row_ptr, csr_src, isd, b2, Fb, N);
  // L3: G(=Fa) = f16(P(z2)) ; B2 = z3 = f16(relu(G@W3+b3))
  agg3_d64_plain_f16<<<ab64, 256, 0, stream>>>(Fb, row_ptr, csr_src, isd, nullptr, Fa, N);
  gemm3_mfma_k64_n128<<<gm, 256, 0, stream>>>(Fa, Wt3, b3, B2, N);
  // L4: B1 = f16(isd*(z3@W4)) ; out = P'+b4 -> OUT (fp32)
  gemm4_mfma_k128_n128<<<gm, 256, 0, stream>>>(B2, Wt4, isd, B1, N);
  agg4_d128_bias_f32<<<ab128, 256, 0, stream>>>(B1, row_ptr, csr_src, isd, b4, OUT, N);
}